// Round 21
// baseline (3881.701 us; speedup 1.0000x reference)
//
#include <hip/hip_runtime.h>
#include <hip/hip_bf16.h>

// Problem constants (fixed by the reference)
#define E_EDGES 200000
#define T_TRIP  2000000
#define N_NODES 20000
#define H_DIM   128
#define INT_DIM 64
#define BAS     8
#define OUT_EMB 256
#define NRAD    6
#define SBF_D   42
#define NB      4

typedef __attribute__((ext_vector_type(8))) __bf16 bf16x8;
typedef __attribute__((ext_vector_type(4))) float f32x4;
typedef unsigned short u16;

__device__ __forceinline__ float silu_f(float v) { return v / (1.0f + __expf(-v)); }

__device__ __forceinline__ u16 f2bf(float f) {
    unsigned int u = __float_as_uint(f);
    u += 0x7FFF + ((u >> 16) & 1);   // RNE
    return (u16)(u >> 16);
}
__device__ __forceinline__ float bf2f(u16 h) {
    return __uint_as_float(((unsigned int)h) << 16);
}

// bf16 LDS helpers (4 consecutive cols, swizzled)
__device__ __forceinline__ void st_bf4(char* T, int row, int col0, int stride,
                                       const float v[4]) {
    ushort4 hh;
    hh.x = f2bf(v[0]); hh.y = f2bf(v[1]); hh.z = f2bf(v[2]); hh.w = f2bf(v[3]);
    int off = (row * stride + col0 * 2) ^ ((row & 7) << 4);
    *reinterpret_cast<ushort4*>(T + off) = hh;
}
__device__ __forceinline__ void ld_bf4(const char* T, int row, int col0, int stride,
                                       float v[4]) {
    int off = (row * stride + col0 * 2) ^ ((row & 7) << 4);
    ushort4 hh = *reinterpret_cast<const ushort4*>(T + off);
    v[0] = bf2f(hh.x); v[1] = bf2f(hh.y); v[2] = bf2f(hh.z); v[3] = bf2f(hh.w);
}

// ---- B-fragment register block: 4 n-tiles (hi+lo) ----
struct BF8x4 { bf16x8 h[4]; bf16x8 l[4]; };

__device__ __forceinline__ BF8x4 loadB128f(const u16* __restrict__ Bh, const u16* __restrict__ Bl,
                                           int k0, int wn, int l15, int khalf)
{
    BF8x4 f;
    #pragma unroll
    for (int n = 0; n < 4; ++n) {
        size_t bo = (size_t)(wn * 64 + n * 16 + l15) * 128 + k0 + khalf;
        f.h[n] = *reinterpret_cast<const bf16x8*>(Bh + bo);
        f.l[n] = *reinterpret_cast<const bf16x8*>(Bl + bo);
    }
    return f;
}
__device__ __forceinline__ BF8x4 loadB64f(const u16* __restrict__ Bh, const u16* __restrict__ Bl,
                                          int k0, int wn, int l15, int khalf)
{
    BF8x4 f;
    #pragma unroll
    for (int n = 0; n < 4; ++n) {
        size_t bo = (size_t)(wn * 64 + n * 16 + l15) * 64 + k0 + khalf;
        f.h[n] = *reinterpret_cast<const bf16x8*>(Bh + bo);
        f.l[n] = *reinterpret_cast<const bf16x8*>(Bl + bo);
    }
    return f;
}
__device__ __forceinline__ BF8x4 loadB256f(const u16* __restrict__ Bh, const u16* __restrict__ Bl,
                                           int k0, int wn, int l15, int khalf)
{
    BF8x4 f;
    #pragma unroll
    for (int n = 0; n < 4; ++n) {
        size_t bo = (size_t)(wn * 64 + n * 16 + l15) * 256 + k0 + khalf;
        f.h[n] = *reinterpret_cast<const bf16x8*>(Bh + bo);
        f.l[n] = *reinterpret_cast<const bf16x8*>(Bl + bo);
    }
    return f;
}

// SWAPPED-OPERAND clusters: mfma(W, A) -> lane output row, 4 consecutive cols.
// bf16-only A (2-term), stride 256B
__device__ __forceinline__ void mfma_cluster_T(
    const char* T, int k0, int wm, int l15, int khalf,
    const BF8x4& b, f32x4 acc[2][4])
{
    __builtin_amdgcn_s_setprio(1);
    #pragma unroll
    for (int m = 0; m < 2; ++m) {
        int row = wm * 32 + m * 16 + l15;
        int off = (row * 256 + (k0 + khalf) * 2) ^ ((row & 7) << 4);
        bf16x8 a = *reinterpret_cast<const bf16x8*>(T + off);
        #pragma unroll
        for (int n = 0; n < 4; ++n) {
            acc[m][n] = __builtin_amdgcn_mfma_f32_16x16x32_bf16(b.h[n], a, acc[m][n], 0, 0, 0);
            acc[m][n] = __builtin_amdgcn_mfma_f32_16x16x32_bf16(b.l[n], a, acc[m][n], 0, 0, 0);
        }
    }
    __builtin_amdgcn_s_setprio(0);
}
// bf16-only A (2-term), K=64, stride 128B
__device__ __forceinline__ void mfma_cluster64_T(
    const char* T, int k0, int wm, int l15, int khalf,
    const BF8x4& b, f32x4 acc[2][4])
{
    __builtin_amdgcn_s_setprio(1);
    #pragma unroll
    for (int m = 0; m < 2; ++m) {
        int row = wm * 32 + m * 16 + l15;
        int off = (row * 128 + (k0 + khalf) * 2) ^ ((row & 7) << 4);
        bf16x8 a = *reinterpret_cast<const bf16x8*>(T + off);
        #pragma unroll
        for (int n = 0; n < 4; ++n) {
            acc[m][n] = __builtin_amdgcn_mfma_f32_16x16x32_bf16(b.h[n], a, acc[m][n], 0, 0, 0);
            acc[m][n] = __builtin_amdgcn_mfma_f32_16x16x32_bf16(b.l[n], a, acc[m][n], 0, 0, 0);
        }
    }
    __builtin_amdgcn_s_setprio(0);
}
// bf16-only A (2-term), stride 512B (rows 0..31)
__device__ __forceinline__ void mfma_cluster512_T(
    const char* T, int k0, int l15, int khalf,
    const BF8x4& b, f32x4 acc[2][4])
{
    __builtin_amdgcn_s_setprio(1);
    #pragma unroll
    for (int m = 0; m < 2; ++m) {
        int row = m * 16 + l15;
        int off = (row * 512 + (k0 + khalf) * 2) ^ ((row & 7) << 4);
        bf16x8 a = *reinterpret_cast<const bf16x8*>(T + off);
        #pragma unroll
        for (int n = 0; n < 4; ++n) {
            acc[m][n] = __builtin_amdgcn_mfma_f32_16x16x32_bf16(b.h[n], a, acc[m][n], 0, 0, 0);
            acc[m][n] = __builtin_amdgcn_mfma_f32_16x16x32_bf16(b.l[n], a, acc[m][n], 0, 0, 0);
        }
    }
    __builtin_amdgcn_s_setprio(0);
}

__device__ __forceinline__ void mm128_pipe_T(
    const char* T,
    const u16* __restrict__ Bh, const u16* __restrict__ Bl, BF8x4& pre,
    const u16* __restrict__ nBh, const u16* __restrict__ nBl,
    int wm, int wn, int l15, int khalf, f32x4 acc[2][4])
{
    BF8x4 c0 = pre;
    BF8x4 c1 = loadB128f(Bh, Bl, 32, wn, l15, khalf);
    mfma_cluster_T(T, 0, wm, l15, khalf, c0, acc);
    BF8x4 c2 = loadB128f(Bh, Bl, 64, wn, l15, khalf);
    mfma_cluster_T(T, 32, wm, l15, khalf, c1, acc);
    BF8x4 c3 = loadB128f(Bh, Bl, 96, wn, l15, khalf);
    mfma_cluster_T(T, 64, wm, l15, khalf, c2, acc);
    if (nBh) pre = loadB128f(nBh, nBl, 0, wn, l15, khalf);
    mfma_cluster_T(T, 96, wm, l15, khalf, c3, acc);
}
// K=64 bf16-only A pipe (for AGG)
__device__ __forceinline__ void mm64_pipe_T(
    const char* T,
    const u16* __restrict__ Bh, const u16* __restrict__ Bl, BF8x4& pre,
    const u16* __restrict__ nBh, const u16* __restrict__ nBl,
    int wm, int wn, int l15, int khalf, f32x4 acc[2][4])
{
    BF8x4 c0 = pre;
    BF8x4 c1 = loadB64f(Bh, Bl, 32, wn, l15, khalf);
    mfma_cluster64_T(T, 0, wm, l15, khalf, c0, acc);
    if (nBh) pre = loadB128f(nBh, nBl, 0, wn, l15, khalf);
    mfma_cluster64_T(T, 32, wm, l15, khalf, c1, acc);
}

// ---------------------------------------------------------------------------
// Weight prep + fp32->bf16 convert
// ---------------------------------------------------------------------------
__global__ __launch_bounds__(256) void wprep(
    const float* __restrict__ src, u16* __restrict__ hi,
    u16* __restrict__ lo, int K, int N)
{
    int e = blockIdx.x * 256 + threadIdx.x;
    int total = K * N;
    if (e >= total) return;
    size_t base = (size_t)blockIdx.y * total;
    float a = src[base + e];
    int k = e / N, n = e - k * N;
    u16 h = f2bf(a);
    u16 l = f2bf(a - bf2f(h));
    hi[base + (size_t)n * K + k] = h;
    lo[base + (size_t)n * K + k] = l;
}

__global__ __launch_bounds__(256) void cvt_bf(
    const float* __restrict__ src, u16* __restrict__ dst, int n4)
{
    int i = blockIdx.x * 256 + threadIdx.x;
    if (i >= n4) return;
    float4 f = *reinterpret_cast<const float4*>(&src[(size_t)i * 4]);
    ushort4 o;
    o.x = f2bf(f.x); o.y = f2bf(f.y); o.z = f2bf(f.z); o.w = f2bf(f.w);
    *reinterpret_cast<ushort4*>(&dst[(size_t)i * 4]) = o;
}

// ---------------------------------------------------------------------------
// pre_fuse (standalone, only for block b=0); 32KB LDS
// ---------------------------------------------------------------------------
__global__ __launch_bounds__(256, 2) void pre_fuse(
    const u16* __restrict__ X, const float* __restrict__ rbf,
    const float* __restrict__ W1,
    const u16* __restrict__ Wjih, const u16* __restrict__ Wjil, const float* __restrict__ bji,
    const u16* __restrict__ Wkjh, const u16* __restrict__ Wkjl, const float* __restrict__ bkj,
    const float* __restrict__ Wr2,
    const u16* __restrict__ Wdnh, const u16* __restrict__ Wdnl,
    u16* __restrict__ E1, u16* __restrict__ C1)
{
    __shared__ char smem[32768];
    char* XT = smem;              // [64][128] bf16, stride 256
    char* IT = smem + 16384;      // [64][128] bf16 temp, stride 256

    const int tid  = threadIdx.x;
    const int lane = tid & 63;
    const int w    = tid >> 6;
    const int wm   = w >> 1, wn = w & 1;
    const int bm   = blockIdx.x * 64;
    const int l15  = lane & 15;
    const int khalf = (lane >> 4) * 8;
    const int r4   = (lane >> 4) * 4;

    BF8x4 pre = loadB128f(Wjih, Wjil, 0, wn, l15, khalf);

    // stage X [64][128] bf16
    {
        int r  = tid >> 2;
        int c0 = (tid & 3) * 32;
        const u16* p = &X[(size_t)(bm + r) * H_DIM + c0];
        const int swz = (r & 7) << 4;
        #pragma unroll
        for (int q = 0; q < 4; ++q) {
            uint4 v = *reinterpret_cast<const uint4*>(p + q * 8);
            int off = (r * 256 + c0 * 2 + q * 16) ^ swz;
            *reinterpret_cast<uint4*>(XT + off) = v;
        }
    }
    __syncthreads();

    // JI -> E1 (bf16)  (prefetch KJ)
    {
        f32x4 acc[2][4] = {};
        mm128_pipe_T(XT, Wjih, Wjil, pre, Wkjh, Wkjl, wm, wn, l15, khalf, acc);
        #pragma unroll
        for (int n = 0; n < 4; ++n) {
            int col0 = wn * 64 + n * 16 + r4;
            float4 bv = *reinterpret_cast<const float4*>(&bji[col0]);
            #pragma unroll
            for (int m = 0; m < 2; ++m) {
                int row = wm * 32 + m * 16 + l15;
                ushort4 ob;
                ob.x = f2bf(silu_f(acc[m][n][0] + bv.x));
                ob.y = f2bf(silu_f(acc[m][n][1] + bv.y));
                ob.z = f2bf(silu_f(acc[m][n][2] + bv.z));
                ob.w = f2bf(silu_f(acc[m][n][3] + bv.w));
                *reinterpret_cast<ushort4*>(&E1[(size_t)(bm + row) * H_DIM + col0]) = ob;
            }
        }
    }
    // KJ * gate -> IT (bf16 temp)
    {
        f32x4 acc[2][4] = {};
        mm128_pipe_T(XT, Wkjh, Wkjl, pre, nullptr, nullptr, wm, wn, l15, khalf, acc);
        float r8v[2][8];
        #pragma unroll
        for (int m = 0; m < 2; ++m) {
            int grow = bm + wm * 32 + m * 16 + l15;
            const float2* rp = reinterpret_cast<const float2*>(&rbf[(size_t)grow * NRAD]);
            float2 q0 = rp[0], q1 = rp[1], q2 = rp[2];
            float rv[NRAD] = {q0.x, q0.y, q1.x, q1.y, q2.x, q2.y};
            #pragma unroll
            for (int j = 0; j < 8; ++j) r8v[m][j] = 0.f;
            #pragma unroll
            for (int k = 0; k < NRAD; ++k)
                #pragma unroll
                for (int j = 0; j < 8; ++j)
                    r8v[m][j] = fmaf(rv[k], W1[k * BAS + j], r8v[m][j]);
        }
        #pragma unroll
        for (int n = 0; n < 4; ++n) {
            int col0 = wn * 64 + n * 16 + r4;
            float4 bvf = *reinterpret_cast<const float4*>(&bkj[col0]);
            float bv[4] = {bvf.x, bvf.y, bvf.z, bvf.w};
            float wrv[8][4];
            #pragma unroll
            for (int j = 0; j < 8; ++j) {
                float4 wf = *reinterpret_cast<const float4*>(&Wr2[j * H_DIM + col0]);
                wrv[j][0] = wf.x; wrv[j][1] = wf.y; wrv[j][2] = wf.z; wrv[j][3] = wf.w;
            }
            #pragma unroll
            for (int m = 0; m < 2; ++m) {
                int row = wm * 32 + m * 16 + l15;
                float v[4];
                #pragma unroll
                for (int r = 0; r < 4; ++r) {
                    float t = silu_f(acc[m][n][r] + bv[r]);
                    float g = 0.f;
                    #pragma unroll
                    for (int j = 0; j < 8; ++j)
                        g = fmaf(r8v[m][j], wrv[j][r], g);
                    v[r] = t * g;
                }
                st_bf4(IT, row, col0, 256, v);
            }
        }
    }
    __syncthreads();

    // DOWN (N=64), 2-term from IT -> C1 (bf16)
    {
        f32x4 acc[2][2] = {};
        #pragma unroll
        for (int k0 = 0; k0 < 128; k0 += 32) {
            bf16x8 bh[2], bl[2];
            #pragma unroll
            for (int n = 0; n < 2; ++n) {
                size_t bo = (size_t)(wn * 32 + n * 16 + l15) * 128 + k0 + khalf;
                bh[n] = *reinterpret_cast<const bf16x8*>(Wdnh + bo);
                bl[n] = *reinterpret_cast<const bf16x8*>(Wdnl + bo);
            }
            __builtin_amdgcn_s_setprio(1);
            #pragma unroll
            for (int m = 0; m < 2; ++m) {
                int row = wm * 32 + m * 16 + l15;
                int off = (row * 256 + (k0 + khalf) * 2) ^ ((row & 7) << 4);
                bf16x8 a = *reinterpret_cast<const bf16x8*>(IT + off);
                #pragma unroll
                for (int n = 0; n < 2; ++n) {
                    acc[m][n] = __builtin_amdgcn_mfma_f32_16x16x32_bf16(bh[n], a, acc[m][n], 0, 0, 0);
                    acc[m][n] = __builtin_amdgcn_mfma_f32_16x16x32_bf16(bl[n], a, acc[m][n], 0, 0, 0);
                }
            }
            __builtin_amdgcn_s_setprio(0);
        }
        #pragma unroll
        for (int n = 0; n < 2; ++n) {
            int col0 = wn * 32 + n * 16 + r4;
            #pragma unroll
            for (int m = 0; m < 2; ++m) {
                int row = wm * 32 + m * 16 + l15;
                ushort4 ob;
                ob.x = f2bf(silu_f(acc[m][n][0]));
                ob.y = f2bf(silu_f(acc[m][n][1]));
                ob.z = f2bf(silu_f(acc[m][n][2]));
                ob.w = f2bf(silu_f(acc[m][n][3]));
                *reinterpret_cast<ushort4*>(&C1[(size_t)(bm + row) * INT_DIM + col0]) = ob;
            }
        }
    }
}

// ---------------------------------------------------------------------------
// post/out bodies sharing 32KB smem
// ---------------------------------------------------------------------------
struct ChainP {
    const u16 *uph, *upl;
    const u16 *b0h, *b0l, *b1h, *b1l;
    const u16 *lnh, *lnl;
    const u16 *a0h, *a0l, *a1h, *a1l, *a2h, *a2l, *a3h, *a3l;
    const float *bb0, *bb1, *blin, *ba0, *ba1, *ba2, *ba3;
    // fused pre-part for NEXT interaction block (doPre != 0)
    int doPre;
    const float *rbfp, *preW1, *nbji, *nbkj, *nwr2;
    const u16 *njih, *njil, *nkjh, *nkjl, *ndnh, *ndnl;
    u16 *nE1, *nC1;
};
struct OutP {
    const float* TN;
    const u16 *Uh, *Ul; const float* bu;
    const u16 *L0h, *L0l; const float* b0;
    const u16 *L1h, *L1l; const float* b1;
    const u16 *L2h, *L2l; const float* b2;
    const float* Wo; float* P;
};

__device__ __forceinline__ void post_chain_body(
    char* smem, int bx,
    const u16* __restrict__ AGG, const u16* __restrict__ E1,
    const u16* __restrict__ X, const ChainP& p, u16* __restrict__ OUT)
{
    char* SB = smem;             // carrier S bf16 [64][128] stride 256 (16KB)
    char* TB = smem + 16384;     // TMP bf16 [64][128] stride 256 (16KB); AGG staging at start
    char* GB = TB;               // bf16-only AGG, stride 128 (8KB)

    const int tid  = threadIdx.x;
    const int lane = tid & 63;
    const int w    = tid >> 6;
    const int wm   = w >> 1, wn = w & 1;
    const int bm   = bx * 64;
    const int l15  = lane & 15;
    const int khalf = (lane >> 4) * 8;
    const int r4   = (lane >> 4) * 4;

    BF8x4 pre = loadB64f(p.uph, p.upl, 0, wn, l15, khalf);

    // stage AGG [64][64] bf16 (stride 128)
    {
        int r  = tid >> 2;
        int c0 = (tid & 3) * 16;
        const ushort4* pg = reinterpret_cast<const ushort4*>(&AGG[(size_t)(bm + r) * INT_DIM + c0]);
        const int swz = (r & 7) << 4;
        #pragma unroll
        for (int q = 0; q < 4; ++q) {
            ushort4 v = pg[q];
            int off = (r * 128 + c0 * 2 + q * 8) ^ swz;
            *reinterpret_cast<ushort4*>(GB + off) = v;
        }
    }
    __syncthreads();

    f32x4 acc[2][4];
    #define ZACC { _Pragma("unroll") for (int m = 0; m < 2; ++m) \
                   _Pragma("unroll") for (int n = 0; n < 4; ++n) \
                       acc[m][n] = f32x4{0.f, 0.f, 0.f, 0.f}; }

    // S1: UP (K=64, 2-term), h0 = E1 + silu -> S (bf16) ; prefetch Wb0
    ZACC
    mm64_pipe_T(GB, p.uph, p.upl, pre, p.b0h, p.b0l, wm, wn, l15, khalf, acc);
    #pragma unroll
    for (int n = 0; n < 4; ++n) {
        int col0 = wn * 64 + n * 16 + r4;
        #pragma unroll
        for (int m = 0; m < 2; ++m) {
            int row = wm * 32 + m * 16 + l15;
            ushort4 e = *reinterpret_cast<const ushort4*>(&E1[(size_t)(bm + row) * H_DIM + col0]);
            float v[4];
            v[0] = bf2f(e.x) + silu_f(acc[m][n][0]);
            v[1] = bf2f(e.y) + silu_f(acc[m][n][1]);
            v[2] = bf2f(e.z) + silu_f(acc[m][n][2]);
            v[3] = bf2f(e.w) + silu_f(acc[m][n][3]);
            st_bf4(SB, row, col0, 256, v);
        }
    }
    __syncthreads();

    // PLAIN: S -> TMP (bf16)
    #define STAGE_PLAIN(WH, WL, BIAS, NWH, NWL)                                         \
    {                                                                                   \
        ZACC                                                                            \
        mm128_pipe_T(SB, WH, WL, pre, NWH, NWL, wm, wn, l15, khalf, acc);               \
        _Pragma("unroll")                                                               \
        for (int n = 0; n < 4; ++n) {                                                   \
            int col0 = wn * 64 + n * 16 + r4;                                           \
            float4 bv = *reinterpret_cast<const float4*>(&BIAS[col0]);                  \
            _Pragma("unroll")                                                           \
            for (int m = 0; m < 2; ++m) {                                               \
                int row = wm * 32 + m * 16 + l15;                                       \
                float v[4];                                                             \
                v[0] = silu_f(acc[m][n][0] + bv.x);                                     \
                v[1] = silu_f(acc[m][n][1] + bv.y);                                     \
                v[2] = silu_f(acc[m][n][2] + bv.z);                                     \
                v[3] = silu_f(acc[m][n][3] + bv.w);                                     \
                st_bf4(TB, row, col0, 256, v);                                          \
            }                                                                           \
        }                                                                               \
        __syncthreads();                                                                \
    }

    // RES: TMP(bf16, 2-term) -> S += silu (bf16 carrier)
    #define STAGE_RES(WH, WL, BIAS, NWH, NWL)                                           \
    {                                                                                   \
        ZACC                                                                            \
        mm128_pipe_T(TB, WH, WL, pre, NWH, NWL, wm, wn, l15, khalf, acc);               \
        _Pragma("unroll")                                                               \
        for (int n = 0; n < 4; ++n) {                                                   \
            int col0 = wn * 64 + n * 16 + r4;                                           \
            float4 bv = *reinterpret_cast<const float4*>(&BIAS[col0]);                  \
            _Pragma("unroll")                                                           \
            for (int m = 0; m < 2; ++m) {                                               \
                int row = wm * 32 + m * 16 + l15;                                       \
                float v[4];                                                             \
                ld_bf4(SB, row, col0, 256, v);                                          \
                v[0] += silu_f(acc[m][n][0] + bv.x);                                    \
                v[1] += silu_f(acc[m][n][1] + bv.y);                                    \
                v[2] += silu_f(acc[m][n][2] + bv.z);                                    \
                v[3] += silu_f(acc[m][n][3] + bv.w);                                    \
                st_bf4(SB, row, col0, 256, v);                                          \
            }                                                                           \
        }                                                                               \
        __syncthreads();                                                                \
    }

    // S2: temp = silu(S@Wb0+bb0); S3: S += silu(temp@Wb1+bb1)
    STAGE_PLAIN(p.b0h, p.b0l, p.bb0, p.b1h, p.b1l)
    STAGE_RES(p.b1h, p.b1l, p.bb1, p.lnh, p.lnl)

    // S4: x1 = silu(S@Wlin+blin) + X -> S in-place (barrier between read & write)
    {
        ZACC
        mm128_pipe_T(SB, p.lnh, p.lnl, pre, p.a0h, p.a0l, wm, wn, l15, khalf, acc);
        __syncthreads();   // all waves done reading S before overwrite
        #pragma unroll
        for (int n = 0; n < 4; ++n) {
            int col0 = wn * 64 + n * 16 + r4;
            float4 bv = *reinterpret_cast<const float4*>(&p.blin[col0]);
            #pragma unroll
            for (int m = 0; m < 2; ++m) {
                int row = wm * 32 + m * 16 + l15;
                ushort4 xv = *reinterpret_cast<const ushort4*>(&X[(size_t)(bm + row) * H_DIM + col0]);
                float v[4];
                v[0] = silu_f(acc[m][n][0] + bv.x) + bf2f(xv.x);
                v[1] = silu_f(acc[m][n][1] + bv.y) + bf2f(xv.y);
                v[2] = silu_f(acc[m][n][2] + bv.z) + bf2f(xv.z);
                v[3] = silu_f(acc[m][n][3] + bv.w) + bf2f(xv.w);
                st_bf4(SB, row, col0, 256, v);
            }
        }
        __syncthreads();
    }

    STAGE_PLAIN(p.a0h, p.a0l, p.ba0, p.a1h, p.a1l)
    STAGE_RES(p.a1h, p.a1l, p.ba1, p.a2h, p.a2l)
    STAGE_PLAIN(p.a2h, p.a2l, p.ba2, p.a3h, p.a3l)

    // S8: OUT(bf16) = S + silu(temp@Wa3+ba3); XT(=SB) := bf16(OUT) if doPre
    {
        ZACC
        mm128_pipe_T(TB, p.a3h, p.a3l, pre,
                     p.doPre ? p.njih : nullptr, p.doPre ? p.njil : nullptr,
                     wm, wn, l15, khalf, acc);
        #pragma unroll
        for (int n = 0; n < 4; ++n) {
            int col0 = wn * 64 + n * 16 + r4;
            float4 bv = *reinterpret_cast<const float4*>(&p.ba3[col0]);
            #pragma unroll
            for (int m = 0; m < 2; ++m) {
                int row = wm * 32 + m * 16 + l15;
                float v[4];
                ld_bf4(SB, row, col0, 256, v);
                ushort4 ob;
                ob.x = f2bf(v[0] + silu_f(acc[m][n][0] + bv.x));
                ob.y = f2bf(v[1] + silu_f(acc[m][n][1] + bv.y));
                ob.z = f2bf(v[2] + silu_f(acc[m][n][2] + bv.z));
                ob.w = f2bf(v[3] + silu_f(acc[m][n][3] + bv.w));
                *reinterpret_cast<ushort4*>(&OUT[(size_t)(bm + row) * H_DIM + col0]) = ob;
                if (p.doPre) {
                    int offx = (row * 256 + col0 * 2) ^ ((row & 7) << 4);
                    *reinterpret_cast<ushort4*>(SB + offx) = ob;   // XT = bf16(OUT)
                }
            }
        }
    }

    // ---- fused pre-part for NEXT block: XT=SB holds bf16(x_{b+1}) rows bm..bm+64
    if (p.doPre) {
        char* XT = SB;
        char* IT = TB;
        __syncthreads();   // XT complete before cross-row MFMA reads

        // JI -> nE1 (prefetch KJ)
        {
            ZACC
            mm128_pipe_T(XT, p.njih, p.njil, pre, p.nkjh, p.nkjl, wm, wn, l15, khalf, acc);
            #pragma unroll
            for (int n = 0; n < 4; ++n) {
                int col0 = wn * 64 + n * 16 + r4;
                float4 bv = *reinterpret_cast<const float4*>(&p.nbji[col0]);
                #pragma unroll
                for (int m = 0; m < 2; ++m) {
                    int row = wm * 32 + m * 16 + l15;
                    ushort4 ob;
                    ob.x = f2bf(silu_f(acc[m][n][0] + bv.x));
                    ob.y = f2bf(silu_f(acc[m][n][1] + bv.y));
                    ob.z = f2bf(silu_f(acc[m][n][2] + bv.z));
                    ob.w = f2bf(silu_f(acc[m][n][3] + bv.w));
                    *reinterpret_cast<ushort4*>(&p.nE1[(size_t)(bm + row) * H_DIM + col0]) = ob;
                }
            }
        }
        // KJ * gate -> IT
        {
            ZACC
            mm128_pipe_T(XT, p.nkjh, p.nkjl, pre, nullptr, nullptr, wm, wn, l15, khalf, acc);
            float r8v[2][8];
            #pragma unroll
            for (int m = 0; m < 2; ++m) {
                int grow = bm + wm * 32 + m * 16 + l15;
                const float2* rp = reinterpret_cast<const float2*>(&p.rbfp[(size_t)grow * NRAD]);
                float2 q0 = rp[0], q1 = rp[1], q2 = rp[2];
                float rv[NRAD] = {q0.x, q0.y, q1.x, q1.y, q2.x, q2.y};
                #pragma unroll
                for (int j = 0; j < 8; ++j) r8v[m][j] = 0.f;
                #pragma unroll
                for (int k = 0; k < NRAD; ++k)
                    #pragma unroll
                    for (int j = 0; j < 8; ++j)
                        r8v[m][j] = fmaf(rv[k], p.preW1[k * BAS + j], r8v[m][j]);
            }
            #pragma unroll
            for (int n = 0; n < 4; ++n) {
                int col0 = wn * 64 + n * 16 + r4;
                float4 bvf = *reinterpret_cast<const float4*>(&p.nbkj[col0]);
                float bv[4] = {bvf.x, bvf.y, bvf.z, bvf.w};
                float wrv[8][4];
                #pragma unroll
                for (int j = 0; j < 8; ++j) {
                    float4 wf = *reinterpret_cast<const float4*>(&p.nwr2[j * H_DIM + col0]);
                    wrv[j][0] = wf.x; wrv[j][1] = wf.y; wrv[j][2] = wf.z; wrv[j][3] = wf.w;
                }
                #pragma unroll
                for (int m = 0; m < 2; ++m) {
                    int row = wm * 32 + m * 16 + l15;
                    float v[4];
                    #pragma unroll
                    for (int r = 0; r < 4; ++r) {
                        float t = silu_f(acc[m][n][r] + bv[r]);
                        float g = 0.f;
                        #pragma unroll
                        for (int j = 0; j < 8; ++j)
                            g = fmaf(r8v[m][j], wrv[j][r], g);
                        v[r] = t * g;
                    }
                    st_bf4(IT, row, col0, 256, v);
                }
            }
        }
        __syncthreads();

        // DOWN (N=64), 2-term from IT -> nC1 (bf16)
        {
            f32x4 acc2[2][2] = {};
            #pragma unroll
            for (int k0 = 0; k0 < 128; k0 += 32) {
                bf16x8 bh[2], bl[2];
                #pragma unroll
                for (int n = 0; n < 2; ++n) {
                    size_t bo = (size_t)(wn * 32 + n * 16 + l15) * 128 + k0 + khalf;
                    bh[n] = *reinterpret_cast<const bf16x8*>(p.ndnh + bo);
                    bl[n] = *reinterpret_cast<const bf16x8*>(p.ndnl + bo);
                }
                __builtin_amdgcn_s_setprio(1);
                #pragma unroll
                for (int m = 0; m < 2; ++m) {
                    int row = wm * 32 + m * 16 + l15;
                    int off = (row * 256 + (k0 + khalf) * 2) ^ ((row & 7) << 4);
                    bf16x8 a = *reinterpret_cast<const bf16x8*>(IT + off);
                    #pragma unroll
                    for (int n = 0; n < 2; ++n) {
                        acc2[m][n] = __builtin_amdgcn_mfma_f32_16x16x32_bf16(bh[n], a, acc2[m][n], 0, 0, 0);
                        acc2[m][n] = __builtin_amdgcn_mfma_f32_16x16x32_bf16(bl[n], a, acc2[m][n], 0, 0, 0);
                    }
                }
                __builtin_amdgcn_s_setprio(0);
            }
            #pragma unroll
            for (int n = 0; n < 2; ++n) {
                int col0 = wn * 32 + n * 16 + r4;
                #pragma unroll
                for (int m = 0; m < 2; ++m) {
                    int row = wm * 32 + m * 16 + l15;
                    ushort4 ob;
                    ob.x = f2bf(silu_f(acc2[m][n][0]));
                    ob.y = f2bf(silu_f(acc2[m][n][1]));
                    ob.z = f2bf(silu_f(acc2[m][n][2]));
                    ob.w = f2bf(silu_f(acc2[m][n][3]));
                    *reinterpret_cast<ushort4*>(&p.nC1[(size_t)(bm + row) * INT_DIM + col0]) = ob;
                }
            }
        }
    }
    #undef STAGE_PLAIN
    #undef STAGE_RES
    #undef ZACC
}

// out_chain: 32KB, bf16 S/TMP
__device__ __forceinline__ void out_chain_body(char* smem, int bx, const OutP& o)
{
    char* RA = smem;             // region A (16KB): X bf16 [32][128] stride 256; then TMP bf16 [32][256] stride 512
    char* RB = smem + 16384;     // region B (16KB): S bf16 [32][256] stride 512

    const int tid  = threadIdx.x;
    const int lane = tid & 63;
    const int wn   = tid >> 6;
    const int bm   = bx * 32;
    const int l15  = lane & 15;
    const int khalf = (lane >> 4) * 8;
    const int r4   = (lane >> 4) * 4;

    // stage TN tile [32][128] bf16 (stride 256) into RA
    {
        int r  = tid >> 3;
        int c0 = (tid & 7) * 16;
        const float* p = &o.TN[(size_t)(bm + r) * H_DIM + c0];
        const int swz = (r & 7) << 4;
        #pragma unroll
        for (int q = 0; q < 4; ++q) {
            float4 f = *reinterpret_cast<const float4*>(p + q * 4);
            ushort4 hh;
            hh.x = f2bf(f.x); hh.y = f2bf(f.y); hh.z = f2bf(f.z); hh.w = f2bf(f.w);
            int off = (r * 256 + c0 * 2 + q * 8) ^ swz;
            *reinterpret_cast<ushort4*>(RA + off) = hh;
        }
    }
    __syncthreads();

    f32x4 acc[2][4];
    #define ZACC { _Pragma("unroll") for (int m = 0; m < 2; ++m) \
                   _Pragma("unroll") for (int n = 0; n < 4; ++n) \
                       acc[m][n] = f32x4{0.f, 0.f, 0.f, 0.f}; }

    // up: A=X bf16 (stride 256, rows 0..31, wm=0), out pre-act+bias -> S (RB)
    {
        ZACC
        BF8x4 pre = loadB128f(o.Uh, o.Ul, 0, wn, l15, khalf);
        mm128_pipe_T(RA, o.Uh, o.Ul, pre, nullptr, nullptr, 0, wn, l15, khalf, acc);
        #pragma unroll
        for (int n = 0; n < 4; ++n) {
            int col0 = wn * 64 + n * 16 + r4;
            float4 bv = *reinterpret_cast<const float4*>(&o.bu[col0]);
            #pragma unroll
            for (int m = 0; m < 2; ++m) {
                int row = m * 16 + l15;
                float v[4] = {acc[m][n][0] + bv.x, acc[m][n][1] + bv.y,
                              acc[m][n][2] + bv.z, acc[m][n][3] + bv.w};
                st_bf4(RB, row, col0, 512, v);
            }
        }
        __syncthreads();
    }

    // L0: A=S (RB) -> TMP (RA, X dead after barrier above)
    {
        ZACC
        BF8x4 cur = loadB256f(o.L0h, o.L0l, 0, wn, l15, khalf);
        #pragma unroll
        for (int k = 0; k < 8; ++k) {
            BF8x4 nxt;
            if (k < 7) nxt = loadB256f(o.L0h, o.L0l, 32 * (k + 1), wn, l15, khalf);
            mfma_cluster512_T(RB, 32 * k, l15, khalf, cur, acc);
            if (k < 7) cur = nxt;
        }
        #pragma unroll
        for (int n = 0; n < 4; ++n) {
            int col0 = wn * 64 + n * 16 + r4;
            float4 bv = *reinterpret_cast<const float4*>(&o.b0[col0]);
            #pragma unroll
            for (int m = 0; m < 2; ++m) {
                int row = m * 16 + l15;
                float v[4];
                v[0] = silu_f(acc[m][n][0] + bv.x);
                v[1] = silu_f(acc[m][n][1] + bv.y);
                v[2] = silu_f(acc[m][n][2] + bv.z);
                v[3] = silu_f(acc[m][n][3] + bv.w);
                st_bf4(RA, row, col0, 512, v);
            }
        }
        __syncthreads();
    }

    // L1: A=TMP (RA) -> S (RB)
    {
        ZACC
        BF8x4 cur = loadB256f(o.L1h, o.L1l, 0, wn, l15, khalf);
        #pragma unroll
        for (int k = 0; k < 8; ++k) {
            BF8x4 nxt;
            if (k < 7) nxt = loadB256f(o.L1h, o.L1l, 32 * (k + 1), wn, l15, khalf);
            mfma_cluster512_T(RA, 32 * k, l15, khalf, cur, acc);
            if (k < 7) cur = nxt;
        }
        #pragma unroll
        for (int n = 0; n < 4; ++n) {
            int col0 = wn * 64 + n * 16 + r4;
            float4 bv = *reinterpret_cast<const float4*>(&o.b1[col0]);
            #pragma unroll
            for (int m = 0; m < 2; ++m) {
                int row = m * 16 + l15;
                float v[4];
                v[0] = silu_f(acc[m][n][0] + bv.x);
                v[1] = silu_f(acc[m][n][1] + bv.y);
                v[2] = silu_f(acc[m][n][2] + bv.z);
                v[3] = silu_f(acc[m][n][3] + bv.w);
                st_bf4(RB, row, col0, 512, v);
            }
        }
        __syncthreads();
    }

    // L2: A=S (RB) -> S in-place (barrier between read & write)
    {
        ZACC
        BF8x4 cur = loadB256f(o.L2h, o.L2l, 0, wn, l15, khalf);
        #pragma unroll
        for (int k = 0; k < 8; ++k) {
            BF8x4 nxt;
            if (k < 7) nxt = loadB256f(o.L2h, o.L2l, 32 * (k + 1), wn, l15, khalf);
            mfma_cluster512_T(RB, 32 * k, l15, khalf, cur, acc);
            if (k < 7) cur = nxt;
        }
        __syncthreads();
        #pragma unroll
        for (int n = 0; n < 4; ++n) {
            int col0 = wn * 64 + n * 16 + r4;
            float4 bv = *reinterpret_cast<const float4*>(&o.b2[col0]);
            #pragma unroll
            for (int m = 0; m < 2; ++m) {
                int row = m * 16 + l15;
                float v[4];
                v[0] = silu_f(acc[m][n][0] + bv.x);
                v[1] = silu_f(acc[m][n][1] + bv.y);
                v[2] = silu_f(acc[m][n][2] + bv.z);
                v[3] = silu_f(acc[m][n][3] + bv.w);
                st_bf4(RB, row, col0, 512, v);
            }
        }
        __syncthreads();
    }

    // final: P[bm+row] += dot(S[row][:256], Wo[:256]); 8 threads per row
    {
        int row  = tid >> 3;
        int part = tid & 7;
        float s = 0.f;
        int cbase = part * 32;
        #pragma unroll
        for (int c4 = 0; c4 < 32; c4 += 4) {
            float v[4];
            ld_bf4(RB, row, cbase + c4, 512, v);
            float4 wv = *reinterpret_cast<const float4*>(&o.Wo[cbase + c4]);
            s = fmaf(v[0], wv.x, s);
            s = fmaf(v[1], wv.y, s);
            s = fmaf(v[2], wv.z, s);
            s = fmaf(v[3], wv.w, s);
        }
        s += __shfl_xor(s, 1);
        s += __shfl_xor(s, 2);
        s += __shfl_xor(s, 4);
        if (part == 0) o.P[bm + row] += s;
    }
    #undef ZACC
}

__global__ __launch_bounds__(256, 2) void post_fused(
    int npost,
    const u16* __restrict__ AGG, const u16* __restrict__ E1,
    const u16* __restrict__ X, ChainP p, u16* __restrict__ OUT, OutP o)
{
    __shared__ char smem[32768];
    if ((int)blockIdx.x < npost)
        post_chain_body(smem, blockIdx.x, AGG, E1, X, p, OUT);
    else
        out_chain_body(smem, blockIdx.x - npost, o);
}

// ---------------------------------------------------------------------------
// Fused gather: blocks < GT do triplet aggregation, rest do out_gather.
// ---------------------------------------------------------------------------
__device__ __forceinline__ float dot8_bf(uint4 r, const float* w2) {
    float s;
    s  = bf2f((u16)(r.x)) * w2[0] + bf2f((u16)(r.x >> 16)) * w2[1];
    s += bf2f((u16)(r.y)) * w2[2] + bf2f((u16)(r.y >> 16)) * w2[3];
    s += bf2f((u16)(r.z)) * w2[4] + bf2f((u16)(r.z >> 16)) * w2[5];
    s += bf2f((u16)(r.w)) * w2[6] + bf2f((u16)(r.w >> 16)) * w2[7];
    return s;
}

__device__ __forceinline__ void triplet_body(
    int bx, int nblk,
    const u16* __restrict__ ps8b, const float* __restrict__ Wsb2,
    const u16* __restrict__ xkj, const int* __restrict__ pkj,
    const int* __restrict__ tptr, const int* __restrict__ tcnt,
    u16* __restrict__ agg)
{
    const int lane = threadIdx.x & 63;
    int wid = bx * 4 + (threadIdx.x >> 6);
    const int nw = nblk * 4;
    float w2[BAS];
    #pragma unroll
    for (int j = 0; j < BAS; ++j) w2[j] = Wsb2[j * INT_DIM + lane];

    for (int e = wid; e < E_EDGES; e += nw) {
        int start = tptr[e];
        int end   = start + tcnt[e];
        float acc0 = 0.f, acc1 = 0.f;
        int i = start;
        for (; i + 1 < end; i += 2) {
            uint4 ra = *reinterpret_cast<const uint4*>(&ps8b[(size_t)i * BAS]);
            uint4 rb = *reinterpret_cast<const uint4*>(&ps8b[(size_t)(i + 1) * BAS]);
            int e0 = pkj[i], e1 = pkj[i + 1];
            float s0 = dot8_bf(ra, w2);
            float s1 = dot8_bf(rb, w2);
            acc0 = fmaf(bf2f(xkj[(size_t)e0 * INT_DIM + lane]), s0, acc0);
            acc1 = fmaf(bf2f(xkj[(size_t)e1 * INT_DIM + lane]), s1, acc1);
        }
        if (i < end) {
            uint4 ra = *reinterpret_cast<const uint4*>(&ps8b[(size_t)i * BAS]);
            int e0 = pkj[i];
            acc0 = fmaf(bf2f(xkj[(size_t)e0 * INT_DIM + lane]), dot8_bf(ra, w2), acc0);
        }
        agg[(size_t)e * INT_DIM + lane] = f2bf(acc0 + acc1);
    }
}

__device__ __forceinline__ void out_gather_body(
    int bx, int nblk,
    const float* __restrict__ rbf, const float* __restrict__ Wor,
    const u16* __restrict__ x,
    const int* __restrict__ eptr, const int* __restrict__ ecnt,
    const int* __restrict__ eperm, float* __restrict__ tN)
{
    const int lane = threadIdx.x & 63;
    int wid = bx * 4 + (threadIdx.x >> 6);
    const int nw = nblk * 4;
    float wr0[NRAD], wr1[NRAD];
    #pragma unroll
    for (int k = 0; k < NRAD; ++k) {
        wr0[k] = Wor[k * H_DIM + lane];
        wr1[k] = Wor[k * H_DIM + lane + 64];
    }
    for (int n = wid; n < N_NODES; n += nw) {
        int start = eptr[n];
        int end   = start + ecnt[n];
        float a0 = 0.f, a1 = 0.f;
        for (int i = start; i < end; ++i) {
            int e = eperm[i];
            const float2* rp = reinterpret_cast<const float2*>(&rbf[(size_t)e * NRAD]);
            float2 r0 = rp[0], r1 = rp[1], r2 = rp[2];
            float rA = r0.x*wr0[0] + r0.y*wr0[1] + r1.x*wr0[2]
                     + r1.y*wr0[3] + r2.x*wr0[4] + r2.y*wr0[5];
            float rB = r0.x*wr1[0] + r0.y*wr1[1] + r1.x*wr1[2]
                     + r1.y*wr1[3] + r2.x*wr1[4] + r2.y*wr1[5];
            a0 = fmaf(rA, bf2f(x[(size_t)e * H_DIM + lane]), a0);
            a1 = fmaf(rB, bf2f(x[(size_t)e * H_DIM + lane + 64]), a1);
        }
        tN[(size_t)n * H_DIM + lane] = a0;
        tN[(size_t)n * H_DIM + lane + 64] = a1;
    }
}

__global__ __launch_bounds__(256) void gather_fused(
    int GT,
    const u16* __restrict__ ps8b, const float* __restrict__ Wsb2,
    const u16* __restrict__ xkj, const int* __restrict__ pkj,
    const int* __restrict__ tptr, const int* __restrict__ tcnt,
    u16* __restrict__ agg,
    const float* __restrict__ rbf, const float* __restrict__ Wor,
    const u16* __restrict__ x,
    const int* __restrict__ eptr, const int* __restrict__ ecnt,
    const int* __restrict__ eperm, float* __restrict__ tN)
{
    int bx = blockIdx.x;
    if (bx < GT)
        triplet_body(bx, GT, ps8b, Wsb2, xkj, pkj, tptr, tcnt, agg);
    else
        out_gather_body(bx - GT, gridDim.x - GT, rbf, Wor, x, eptr, ecnt, eperm, tN);
}

// ---------------------------------------------------------------------------
// CSR build kernels
// ---------------------------------------------------------------------------
__global__ __launch_bounds__(256) void csr_count(
    const int* __restrict__ idx, int* __restrict__ cnt, int n)
{
    int i = blockIdx.x * 256 + threadIdx.x;
    if (i < n) atomicAdd(&cnt[idx[i]], 1);
}

__global__ __launch_bounds__(256) void scan_block(
    const int* __restrict__ cnt, int* __restrict__ ptr, int* __restrict__ bsum, int n)
{
    __shared__ int s[256];
    int i = blockIdx.x * 256 + threadIdx.x;
    int v = (i < n) ? cnt[i] : 0;
    s[threadIdx.x] = v;
    __syncthreads();
    #pragma unroll
    for (int off = 1; off < 256; off <<= 1) {
        int t = (threadIdx.x >= off) ? s[threadIdx.x - off] : 0;
        __syncthreads();
        s[threadIdx.x] += t;
        __syncthreads();
    }
    if (i < n) ptr[i] = s[threadIdx.x] - v;   // exclusive
    if (threadIdx.x == 255) bsum[blockIdx.x] = s[255];
}

__global__ __launch_bounds__(1024) void scan_aux(int* __restrict__ bsum, int nb)
{
    __shared__ int s[1024];
    int v = (threadIdx.x < nb) ? bsum[threadIdx.x] : 0;
    s[threadIdx.x] = v;
    __syncthreads();
    #pragma unroll
    for (int off = 1; off < 1024; off <<= 1) {
        int t = (threadIdx.x >= off) ? s[threadIdx.x - off] : 0;
        __syncthreads();
        s[threadIdx.x] += t;
        __syncthreads();
    }
    if (threadIdx.x < nb) bsum[threadIdx.x] = s[threadIdx.x] - v;
}

__global__ __launch_bounds__(256) void scan_add(
    int* __restrict__ ptr, const int* __restrict__ bsum, int n)
{
    int i = blockIdx.x * 256 + threadIdx.x;
    if (i < n) ptr[i] += bsum[blockIdx.x];
}

__global__ __launch_bounds__(256) void csr_fill(
    const int* __restrict__ idx, int* __restrict__ cursor,
    int* __restrict__ perm, int n)
{
    int i = blockIdx.x * 256 + threadIdx.x;
    if (i >= n) return;
    int pos = atomicAdd(&cursor[idx[i]], 1);
    perm[pos] = i;
}

// ---------------------------------------------------------------------------
// One-time: permuted sbf basis for ALL blocks + permuted idx_kj.
// ---------------------------------------------------------------------------
__global__ __launch_bounds__(256) void permute_s8(
    const float* __restrict__ sbf, const float* __restrict__ W1all,
    const int* __restrict__ idx_kj, const int* __restrict__ tperm,
    u16* __restrict__ ps8, int* __restrict__ pkj, int Tcount)
{
    __shared__ float Ws[NB * SBF_D * BAS];
    for (int i = threadIdx.x; i < NB * SBF_D * BAS; i += 256) Ws[i] = W1all[i];
    __syncthreads();
    int i = blockIdx.x * 256 + threadIdx.x;
    if (i >= Tcount) return;
    int t = tperm[i];
    pkj[i] = idx_kj[t];
    float s[SBF_D];
    {
        const float2* p2 = reinterpret_cast<const float2*>(&sbf[(size_t)t * SBF_D]);
        #pragma unroll
        for (int k = 0; k < SBF_D / 2; ++k) {
            float2 v = p2[k];
            s[2 * k] = v.x; s[2 * k + 1] = v.y;
        }
    }
    #pragma unroll
    for (int b = 0; b < NB; ++b) {
        const float* Wb_ = &Ws[b * SBF_D * BAS];
        float acc[BAS] = {};
        for (int k = 0; k < SBF_D; ++k) {
            float sv = s[k];
            #pragma unroll
            for (int j = 0; j < BAS; ++j)
                acc[j] = fmaf(sv, Wb_[k * BAS + j], acc[j]);
        }
        ushort4 o0 = make_ushort4(f2bf(acc[0]), f2bf(acc[1]), f2bf(acc[2]), f2bf(acc[3]));
        ushort4 o1 = make_ushort4(f2bf(acc[4]), f2bf(acc[5]), f2bf(acc[6]), f2bf(acc[7]));
        u16* op = &ps8[((size_t)b * Tcount + i) * BAS];
        *reinterpret_cast<ushort4*>(op) = o0;
        *reinterpret_cast<ushort4*>(op + 4) = o1;
    }
}

// ---------------------------------------------------------------------------
extern "C" void kernel_launch(void* const* d_in, const int* in_sizes, int n_in,
                              void* d_out, int out_size, void* d_ws, size_t ws_size,
                              hipStream_t stream)
{
    const float* x_in    = (const float*)d_in[0];
    const float* rbf     = (const float*)d_in[1];
    const float* sbf     = (const float*)d_in[2];
    const float* W_rbf1  = (const float*)d_in[3];
    const float* W_rbf2  = (const float*)d_in[4];
    const float* W_sbf1  = (const float*)d_in[5];
    const float* W_sbf2  = (const float*)d_in[6];
    const float* W_kj    = (const float*)d_in[7];
    const float* b_kj    = (const float*)d_in[8];
    const float* W_ji    = (const float*)d_in[9];
    const float* b_ji    = (const float*)d_in[10];
    const float* W_down  = (const float*)d_in[11];
    const float* W_up    = (const float*)d_in[12];
    const float* Wb      = (const float*)d_in[13];
    const float* bb      = (const float*)d_in[14];
    const float* Wa      = (const float*)d_in[15];
    const float* ba      = (const float*)d_in[16];
    const float* W_lin   = (const float*)d_in[17];
    const float* b_lin   = (const float*)d_in[18];
    const float* Wo_rbf  = (const float*)d_in[19];
    const float* Wo_up   = (const float*)d_in[20];
    const float* bo_up   = (const float*)d_in[21];
    const float* Wo_lins = (const float*)d_in[22];
    const float* bo_lins = (const float*)d_in[23];
    const float* Wo_out  = (const float*)d_in[24];
    const int*   idx_kj  = (const int*)d_in[25];
    const int*   idx_ji  = (const int*)d_in[26];
    const int*   idx_i   = (const int*)d_in[27];

    // workspace carve-up
    char* ws = (char*)d_ws;
    size_t off = 0;
    auto alloc = [&](size_t bytes) -> void* {
        void* p = (void*)(ws + off);
        off += (bytes + 255) & ~(size_t)255;
        return p;
    };
    u16*   X0B = (u16*)alloc((size_t)E_EDGES * H_DIM * 2);   // bf16 input x
    u16*   XAB = (u16*)alloc((size_t)E_EDGES * H_DIM * 2);
    u16*   XBB = (u16*)alloc((size_t)E_EDGES * H_DIM * 2);
    u16*   E1B = (u16*)alloc((size_t)E_EDGES * H_DIM * 2);   // bf16 E1
    u16*   C1B = (u16*)alloc((size_t)E_EDGES * INT_DIM * 2); // bf16 C1
    u16*   C2B = (u16*)alloc((size_t)E_EDGES * INT_DIM * 2); // bf16 C2
    float* TN  = (float*)alloc((size_t)N_NODES * H_DIM * 4);
    // split-bf16 transposed weights
    u16* HKJ = (u16*)alloc(4  * 16384 * 2); u16* LKJ = (u16*)alloc(4  * 16384 * 2);
    u16* HJI = (u16*)alloc(4  * 16384 * 2); u16* LJI = (u16*)alloc(4  * 16384 * 2);
    u16* HDN = (u16*)alloc(4  * 8192  * 2); u16* LDN = (u16*)alloc(4  * 8192  * 2);
    u16* HUP = (u16*)alloc(4  * 8192  * 2); u16* LUP = (u16*)alloc(4  * 8192  * 2);
    u16* HWB = (u16*)alloc(8  * 16384 * 2); u16* LWB = (u16*)alloc(8  * 16384 * 2);
    u16* HWA = (u16*)alloc(16 * 16384 * 2); u16* LWA = (u16*)alloc(16 * 16384 * 2);
    u16* HLN = (u16*)alloc(4  * 16384 * 2); u16* LLN = (u16*)alloc(4  * 16384 * 2);
    u16* HOU = (u16*)alloc(5  * 32768 * 2); u16* LOU = (u16*)alloc(5  * 32768 * 2);
    u16* HOL = (u16*)alloc(15 * 65536 * 2); u16* LOL = (u16*)alloc(15 * 65536 * 2);
    // CSR structures
    int* tcnt  = (int*)alloc((size_t)E_EDGES * 4);
    int* tptr  = (int*)alloc((size_t)E_EDGES * 4);
    int* tcur  = (int*)alloc((size_t)E_EDGES * 4);
    int* tperm = (int*)alloc((size_t)T_TRIP * 4);
    int* tbsum = (int*)alloc(1024 * 4);
    int* ecnt  = (int*)alloc((size_t)N_NODES * 4);
    int* eptr  = (int*)alloc((size_t)N_NODES * 4);
    int* ecur  = (int*)alloc((size_t)N_NODES * 4);
    int* eperm = (int*)alloc((size_t)E_EDGES * 4);
    int* ebsum = (int*)alloc(1024 * 4);
    // permuted triplet stream
    u16* PS8 = (u16*)alloc((size_t)NB * T_TRIP * BAS * 2);
    int* PKJ = (int*)alloc((size_t)T_TRIP * 4);
    (void)ws_size;

    auto prep = [&](const float* src, u16* hi, u16* lo, int K, int N, int cnt) {
        dim3 g((K * N + 255) / 256, cnt);
        hipLaunchKernelGGL(wprep, g, dim3(256), 0, stream, src, hi, lo, K, N);
    };
    prep(W_kj,    HKJ, LKJ, 128, 128, 4);
    prep(W_ji,    HJI, LJI, 128, 128, 4);
    prep(W_down,  HDN, LDN, 128, 64,  4);
    prep(W_up,    HUP, LUP, 64,  128, 4);
    prep(Wb,      HWB, LWB, 128, 128, 8);
    prep(Wa,      HWA, LWA, 128, 128, 16);
    prep(W_lin,   HLN, LLN, 128, 128, 4);
    prep(Wo_up,   HOU, LOU, 128, 256, 5);
    prep(Wo_lins, HOL, LOL, 256, 256, 15);

    // ---- convert input x to bf16
    hipLaunchKernelGGL(cvt_bf, dim3((E_EDGES * H_DIM / 4 + 255) / 256), dim3(256), 0, stream,
                       x_in, X0B, E_EDGES * H_DIM / 4);

    // ---- build triplet CSR (idx_ji: T entries -> E buckets)
    {
        const int nbT = (E_EDGES + 255) / 256;
        hipMemsetAsync(tcnt, 0, (size_t)E_EDGES * 4, stream);
        hipLaunchKernelGGL(csr_count, dim3((T_TRIP + 255) / 256), dim3(256), 0, stream,
                           idx_ji, tcnt, T_TRIP);
        hipLaunchKernelGGL(scan_block, dim3(nbT), dim3(256), 0, stream, tcnt, tptr, tbsum, E_EDGES);
        hipLaunchKernelGGL(scan_aux, dim3(1), dim3(1024), 0, stream, tbsum, nbT);
        hipLaunchKernelGGL(scan_add, dim3(nbT), dim3(256), 0, stream, tptr, tbsum, E_EDGES);
        hipMemcpyAsync(tcur, tptr, (size_t)E_EDGES * 4, hipMemcpyDeviceToDevice, stream);
        hipLaunchKernelGGL(csr_fill, dim3((T_TRIP + 255) / 256), dim3(256), 0, stream,
                           idx_ji, tcur, tperm, T_TRIP);
    }
    // ---- build node CSR (idx_i: E entries -> N buckets)
    {
        const int nbN = (N_NODES + 255) / 256;
        hipMemsetAsync(ecnt, 0, (size_t)N_NODES * 4, stream);
        hipLaunchKernelGGL(csr_count, dim3((E_EDGES + 255) / 256), dim3(256), 0, stream,
                           idx_i, ecnt, E_EDGES);
        hipLaunchKernelGGL(scan_block, dim3(nbN), dim3(256), 0, stream, ecnt, eptr, ebsum, N_NODES);
        hipLaunchKernelGGL(scan_aux, dim3(1), dim3(1024), 0, stream, ebsum, nbN);
        hipLaunchKernelGGL(scan_add, dim3(nbN), dim3(256), 0, stream, eptr, ebsum, N_NODES);
        hipMemcpyAsync(ecur, eptr, (size_t)N_NODES * 4, hipMemcpyDeviceToDevice, stream);
        hipLaunchKernelGGL(csr_fill, dim3((E_EDGES + 255) / 256), dim3(256), 0, stream,
                           idx_i, ecur, eperm, E_EDGES);
    }
    // ---- one-time permuted sbf basis for all blocks
    hipLaunchKernelGGL(permute_s8, dim3((T_TRIP + 255) / 256), dim3(256), 0, stream,
                       sbf, W_sbf1, idx_kj, tperm, PS8, PKJ, T_TRIP);

    float* P = (float*)d_out;
    hipMemsetAsync(P, 0, (size_t)N_NODES * sizeof(float), stream);

    auto make_outp = [&](int ob) {
        OutP o;
        o.TN = TN;
        o.Uh = HOU + (size_t)ob * 32768; o.Ul = LOU + (size_t)ob * 32768;
        o.bu = bo_up + (size_t)ob * OUT_EMB;
        o.L0h = HOL + (size_t)(ob * 3 + 0) * 65536; o.L0l = LOL + (size_t)(ob * 3 + 0) * 65536;
        o.b0 = bo_lins + (size_t)(ob * 3 + 0) * OUT_EMB;
        o.L1h = HOL + (size_t)(ob * 3 + 1) * 65536; o.L1l = LOL + (size_t)(ob * 3 + 1) * 65536;
        o.b1 = bo_lins + (size_t)(ob * 3 + 1) * OUT_EMB;
        o.L2h = HOL + (size_t)(ob * 3 + 2) * 65536; o.L2l = LOL + (size_t)(ob * 3 + 2) * 65536;
        o.b2 = bo_lins + (size_t)(ob * 3 + 2) * OUT_EMB;
        o.Wo = Wo_out + (size_t)ob * OUT_EMB;
        o.P = P;
        return o;
    };

    const u16* xcur = X0B;
    const int EB = E_EDGES / 64;  // 3125
    const int GT = 3584;          // triplet blocks (work ratio ~10:1 vs out_gather)
    const int GO = 512;           // out_gather blocks

    // standalone pre_fuse only for b=0
    hipLaunchKernelGGL(pre_fuse, dim3(EB), dim3(256), 0, stream,
                       xcur, rbf, W_rbf1,
                       HJI, LJI, b_ji,
                       HKJ, LKJ, b_kj,
                       W_rbf2,
                       HDN, LDN,
                       E1B, C1B);

    for (int b = 0; b < NB; ++b) {
        u16* xnext = (b % 2 == 0) ? XAB : XBB;
        // 1) triplet aggregation || out_gather(ob=b, xcur)
        hipLaunchKernelGGL(gather_fused, dim3(GT + GO), dim3(256), 0, stream,
                           GT,
                           PS8 + (size_t)b * T_TRIP * BAS, W_sbf2 + (size_t)b * BAS * INT_DIM,
                           C1B, PKJ, tptr, tcnt, C2B,
                           rbf, Wo_rbf + (size_t)b * NRAD * H_DIM, xcur,
                           eptr, ecnt, eperm, TN);
        // 2) post_chain(b) [+ fused pre(b+1)] || out_chain(ob=b)
        ChainP cp;
        cp.uph = HUP + (size_t)b * 8192;  cp.upl = LUP + (size_t)b * 8192;
        cp.b0h = HWB + (size_t)(b * 2 + 0) * 16384; cp.b0l = LWB + (size_t)(b * 2 + 0) * 16384;
        cp.b1h = HWB + (size_t)(b * 2 + 1) * 16384; cp.b1l = LWB + (size_t)(b * 2 + 1) * 16384;
        cp.lnh = HLN + (size_t)b * 16384; cp.lnl = LLN + (size_t)b * 16384;
        cp.a0h = HWA + (size_t)(b * 4 + 0) * 16384; cp.a0l = LWA + (size_t)(b * 4 + 0) * 16384;
        cp.a1h = HWA + (size_t)(b * 4 + 1) * 16384; cp.a1l = LWA + (size_t)(b * 4 + 1) * 16384;
        cp.a2h = HWA + (size_t)(b * 4 + 2) * 16384; cp.a2l = LWA + (size_t)(b * 4 + 2) * 16384;
        cp.a3h = HWA + (size_t)(b * 4 + 3) * 16384; cp.a3l = LWA + (size_t)(b * 4 + 3) * 16384;
        cp.bb0 = bb + (size_t)(b * 2 + 0) * H_DIM;
        cp.bb1 = bb + (size_t)(b * 2 + 1) * H_DIM;
        cp.blin = b_lin + (size_t)b * H_DIM;
        cp.ba0 = ba + (size_t)(b * 4 + 0) * H_DIM;
        cp.ba1 = ba + (size_t)(b * 4 + 1) * H_DIM;
        cp.ba2 = ba + (size_t)(b * 4 + 2) * H_DIM;
        cp.ba3 = ba + (size_t)(b * 4 + 3) * H_DIM;
        if (b < NB - 1) {
            int nb_ = b + 1;
            cp.doPre = 1;
            cp.rbfp  = rbf;
            cp.preW1 = W_rbf1 + (size_t)nb_ * NRAD * BAS;
            cp.njih = HJI + (size_t)nb_ * 16384; cp.njil = LJI + (size_t)nb_ * 16384;
            cp.nbji = b_ji + (size_t)nb_ * H_DIM;
            cp.nkjh = HKJ + (size_t)nb_ * 16384; cp.nkjl = LKJ + (size_t)nb_ * 16384;
            cp.nbkj = b_kj + (size_t)nb_ * H_DIM;
            cp.nwr2 = W_rbf2 + (size_t)nb_ * BAS * H_DIM;
            cp.ndnh = HDN + (size_t)nb_ * 8192; cp.ndnl = LDN + (size_t)nb_ * 8192;
            cp.nE1  = E1B; cp.nC1 = C1B;
        } else {
            cp.doPre = 0;
            cp.rbfp = nullptr; cp.preW1 = nullptr;
            cp.njih = nullptr; cp.njil = nullptr; cp.nbji = nullptr;
            cp.nkjh = nullptr; cp.nkjl = nullptr; cp.nbkj = nullptr;
            cp.nwr2 = nullptr; cp.ndnh = nullptr; cp.ndnl = nullptr;
            cp.nE1 = nullptr; cp.nC1 = nullptr;
        }
        OutP op = make_outp(b);
        hipLaunchKernelGGL(post_fused, dim3(EB + N_NODES / 32), dim3(256), 0, stream,
                           EB, C2B, E1B, xcur, cp, xnext, op);
        xcur = xnext;
    }
    // final output block ob=NB: out_gather(x_NB) then out_chain
    {
        OutP op = make_outp(NB);
        ChainP cp = {};  // unused
        hipLaunchKernelGGL(gather_fused, dim3(2048), dim3(256), 0, stream,
                           0,
                           PS8, W_sbf2, C1B, PKJ, tptr, tcnt, C2B,
                           rbf, Wo_rbf + (size_t)NB * NRAD * H_DIM, xcur,
                           eptr, ecnt, eperm, TN);
        hipLaunchKernelGGL(post_fused, dim3(N_NODES / 32), dim3(256), 0, stream,
                           0, C2B, E1B, xcur, cp, XAB, op);
    }
}

// Round 22
// 3780.591 us; speedup vs baseline: 1.0267x; 1.0267x over previous
//
#include <hip/hip_runtime.h>
#include <hip/hip_bf16.h>

// Problem constants (fixed by the reference)
#define E_EDGES 200000
#define T_TRIP  2000000
#define N_NODES 20000
#define H_DIM   128
#define INT_DIM 64
#define BAS     8
#define OUT_EMB 256
#define NRAD    6
#define SBF_D   42
#define NB      4

typedef __attribute__((ext_vector_type(8))) __bf16 bf16x8;
typedef __attribute__((ext_vector_type(4))) float f32x4;
typedef unsigned short u16;

__device__ __forceinline__ float silu_f(float v) { return v / (1.0f + __expf(-v)); }

__device__ __forceinline__ u16 f2bf(float f) {
    unsigned int u = __float_as_uint(f);
    u += 0x7FFF + ((u >> 16) & 1);   // RNE
    return (u16)(u >> 16);
}
__device__ __forceinline__ float bf2f(u16 h) {
    return __uint_as_float(((unsigned int)h) << 16);
}

// bf16 LDS helpers (4 consecutive cols, swizzled)
__device__ __forceinline__ void st_bf4(char* T, int row, int col0, int stride,
                                       const float v[4]) {
    ushort4 hh;
    hh.x = f2bf(v[0]); hh.y = f2bf(v[1]); hh.z = f2bf(v[2]); hh.w = f2bf(v[3]);
    int off = (row * stride + col0 * 2) ^ ((row & 7) << 4);
    *reinterpret_cast<ushort4*>(T + off) = hh;
}
__device__ __forceinline__ void ld_bf4(const char* T, int row, int col0, int stride,
                                       float v[4]) {
    int off = (row * stride + col0 * 2) ^ ((row & 7) << 4);
    ushort4 hh = *reinterpret_cast<const ushort4*>(T + off);
    v[0] = bf2f(hh.x); v[1] = bf2f(hh.y); v[2] = bf2f(hh.z); v[3] = bf2f(hh.w);
}

// ---- B-fragment register block: 4 n-tiles (hi+lo) ----
struct BF8x4 { bf16x8 h[4]; bf16x8 l[4]; };

__device__ __forceinline__ BF8x4 loadB128f(const u16* __restrict__ Bh, const u16* __restrict__ Bl,
                                           int k0, int wn, int l15, int khalf)
{
    BF8x4 f;
    #pragma unroll
    for (int n = 0; n < 4; ++n) {
        size_t bo = (size_t)(wn * 64 + n * 16 + l15) * 128 + k0 + khalf;
        f.h[n] = *reinterpret_cast<const bf16x8*>(Bh + bo);
        f.l[n] = *reinterpret_cast<const bf16x8*>(Bl + bo);
    }
    return f;
}
__device__ __forceinline__ BF8x4 loadB64f(const u16* __restrict__ Bh, const u16* __restrict__ Bl,
                                          int k0, int wn, int l15, int khalf)
{
    BF8x4 f;
    #pragma unroll
    for (int n = 0; n < 4; ++n) {
        size_t bo = (size_t)(wn * 64 + n * 16 + l15) * 64 + k0 + khalf;
        f.h[n] = *reinterpret_cast<const bf16x8*>(Bh + bo);
        f.l[n] = *reinterpret_cast<const bf16x8*>(Bl + bo);
    }
    return f;
}
__device__ __forceinline__ BF8x4 loadB256f(const u16* __restrict__ Bh, const u16* __restrict__ Bl,
                                           int k0, int wn, int l15, int khalf)
{
    BF8x4 f;
    #pragma unroll
    for (int n = 0; n < 4; ++n) {
        size_t bo = (size_t)(wn * 64 + n * 16 + l15) * 256 + k0 + khalf;
        f.h[n] = *reinterpret_cast<const bf16x8*>(Bh + bo);
        f.l[n] = *reinterpret_cast<const bf16x8*>(Bl + bo);
    }
    return f;
}

// SWAPPED-OPERAND clusters: mfma(W, A) -> lane output row, 4 consecutive cols.
// bf16-only A (2-term), stride 256B
__device__ __forceinline__ void mfma_cluster_T(
    const char* T, int k0, int wm, int l15, int khalf,
    const BF8x4& b, f32x4 acc[2][4])
{
    __builtin_amdgcn_s_setprio(1);
    #pragma unroll
    for (int m = 0; m < 2; ++m) {
        int row = wm * 32 + m * 16 + l15;
        int off = (row * 256 + (k0 + khalf) * 2) ^ ((row & 7) << 4);
        bf16x8 a = *reinterpret_cast<const bf16x8*>(T + off);
        #pragma unroll
        for (int n = 0; n < 4; ++n) {
            acc[m][n] = __builtin_amdgcn_mfma_f32_16x16x32_bf16(b.h[n], a, acc[m][n], 0, 0, 0);
            acc[m][n] = __builtin_amdgcn_mfma_f32_16x16x32_bf16(b.l[n], a, acc[m][n], 0, 0, 0);
        }
    }
    __builtin_amdgcn_s_setprio(0);
}
// bf16-only A (2-term), K=64, stride 128B
__device__ __forceinline__ void mfma_cluster64_T(
    const char* T, int k0, int wm, int l15, int khalf,
    const BF8x4& b, f32x4 acc[2][4])
{
    __builtin_amdgcn_s_setprio(1);
    #pragma unroll
    for (int m = 0; m < 2; ++m) {
        int row = wm * 32 + m * 16 + l15;
        int off = (row * 128 + (k0 + khalf) * 2) ^ ((row & 7) << 4);
        bf16x8 a = *reinterpret_cast<const bf16x8*>(T + off);
        #pragma unroll
        for (int n = 0; n < 4; ++n) {
            acc[m][n] = __builtin_amdgcn_mfma_f32_16x16x32_bf16(b.h[n], a, acc[m][n], 0, 0, 0);
            acc[m][n] = __builtin_amdgcn_mfma_f32_16x16x32_bf16(b.l[n], a, acc[m][n], 0, 0, 0);
        }
    }
    __builtin_amdgcn_s_setprio(0);
}
// bf16-only A (2-term), stride 512B (rows 0..31)
__device__ __forceinline__ void mfma_cluster512_T(
    const char* T, int k0, int l15, int khalf,
    const BF8x4& b, f32x4 acc[2][4])
{
    __builtin_amdgcn_s_setprio(1);
    #pragma unroll
    for (int m = 0; m < 2; ++m) {
        int row = m * 16 + l15;
        int off = (row * 512 + (k0 + khalf) * 2) ^ ((row & 7) << 4);
        bf16x8 a = *reinterpret_cast<const bf16x8*>(T + off);
        #pragma unroll
        for (int n = 0; n < 4; ++n) {
            acc[m][n] = __builtin_amdgcn_mfma_f32_16x16x32_bf16(b.h[n], a, acc[m][n], 0, 0, 0);
            acc[m][n] = __builtin_amdgcn_mfma_f32_16x16x32_bf16(b.l[n], a, acc[m][n], 0, 0, 0);
        }
    }
    __builtin_amdgcn_s_setprio(0);
}

__device__ __forceinline__ void mm128_pipe_T(
    const char* T,
    const u16* __restrict__ Bh, const u16* __restrict__ Bl, BF8x4& pre,
    const u16* __restrict__ nBh, const u16* __restrict__ nBl,
    int wm, int wn, int l15, int khalf, f32x4 acc[2][4])
{
    BF8x4 c0 = pre;
    BF8x4 c1 = loadB128f(Bh, Bl, 32, wn, l15, khalf);
    mfma_cluster_T(T, 0, wm, l15, khalf, c0, acc);
    BF8x4 c2 = loadB128f(Bh, Bl, 64, wn, l15, khalf);
    mfma_cluster_T(T, 32, wm, l15, khalf, c1, acc);
    BF8x4 c3 = loadB128f(Bh, Bl, 96, wn, l15, khalf);
    mfma_cluster_T(T, 64, wm, l15, khalf, c2, acc);
    if (nBh) pre = loadB128f(nBh, nBl, 0, wn, l15, khalf);
    mfma_cluster_T(T, 96, wm, l15, khalf, c3, acc);
}
// K=64 bf16-only A pipe (for AGG)
__device__ __forceinline__ void mm64_pipe_T(
    const char* T,
    const u16* __restrict__ Bh, const u16* __restrict__ Bl, BF8x4& pre,
    const u16* __restrict__ nBh, const u16* __restrict__ nBl,
    int wm, int wn, int l15, int khalf, f32x4 acc[2][4])
{
    BF8x4 c0 = pre;
    BF8x4 c1 = loadB64f(Bh, Bl, 32, wn, l15, khalf);
    mfma_cluster64_T(T, 0, wm, l15, khalf, c0, acc);
    if (nBh) pre = loadB128f(nBh, nBl, 0, wn, l15, khalf);
    mfma_cluster64_T(T, 32, wm, l15, khalf, c1, acc);
}

// ---------------------------------------------------------------------------
// Weight prep + fp32->bf16 convert
// ---------------------------------------------------------------------------
__global__ __launch_bounds__(256) void wprep(
    const float* __restrict__ src, u16* __restrict__ hi,
    u16* __restrict__ lo, int K, int N)
{
    int e = blockIdx.x * 256 + threadIdx.x;
    int total = K * N;
    if (e >= total) return;
    size_t base = (size_t)blockIdx.y * total;
    float a = src[base + e];
    int k = e / N, n = e - k * N;
    u16 h = f2bf(a);
    u16 l = f2bf(a - bf2f(h));
    hi[base + (size_t)n * K + k] = h;
    lo[base + (size_t)n * K + k] = l;
}

__global__ __launch_bounds__(256) void cvt_bf(
    const float* __restrict__ src, u16* __restrict__ dst, int n4)
{
    int i = blockIdx.x * 256 + threadIdx.x;
    if (i >= n4) return;
    float4 f = *reinterpret_cast<const float4*>(&src[(size_t)i * 4]);
    ushort4 o;
    o.x = f2bf(f.x); o.y = f2bf(f.y); o.z = f2bf(f.z); o.w = f2bf(f.w);
    *reinterpret_cast<ushort4*>(&dst[(size_t)i * 4]) = o;
}

// ---------------------------------------------------------------------------
// pre_fuse (standalone, only for block b=0); 32KB LDS
// ---------------------------------------------------------------------------
__global__ __launch_bounds__(256, 2) void pre_fuse(
    const u16* __restrict__ X, const float* __restrict__ rbf,
    const float* __restrict__ W1,
    const u16* __restrict__ Wjih, const u16* __restrict__ Wjil, const float* __restrict__ bji,
    const u16* __restrict__ Wkjh, const u16* __restrict__ Wkjl, const float* __restrict__ bkj,
    const float* __restrict__ Wr2,
    const u16* __restrict__ Wdnh, const u16* __restrict__ Wdnl,
    u16* __restrict__ E1, u16* __restrict__ C1)
{
    __shared__ char smem[32768];
    char* XT = smem;              // [64][128] bf16, stride 256
    char* IT = smem + 16384;      // [64][128] bf16 temp, stride 256

    const int tid  = threadIdx.x;
    const int lane = tid & 63;
    const int w    = tid >> 6;
    const int wm   = w >> 1, wn = w & 1;
    const int bm   = blockIdx.x * 64;
    const int l15  = lane & 15;
    const int khalf = (lane >> 4) * 8;
    const int r4   = (lane >> 4) * 4;

    BF8x4 pre = loadB128f(Wjih, Wjil, 0, wn, l15, khalf);

    // stage X [64][128] bf16
    {
        int r  = tid >> 2;
        int c0 = (tid & 3) * 32;
        const u16* p = &X[(size_t)(bm + r) * H_DIM + c0];
        const int swz = (r & 7) << 4;
        #pragma unroll
        for (int q = 0; q < 4; ++q) {
            uint4 v = *reinterpret_cast<const uint4*>(p + q * 8);
            int off = (r * 256 + c0 * 2 + q * 16) ^ swz;
            *reinterpret_cast<uint4*>(XT + off) = v;
        }
    }
    __syncthreads();

    // JI -> E1 (bf16)  (prefetch KJ)
    {
        f32x4 acc[2][4] = {};
        mm128_pipe_T(XT, Wjih, Wjil, pre, Wkjh, Wkjl, wm, wn, l15, khalf, acc);
        #pragma unroll
        for (int n = 0; n < 4; ++n) {
            int col0 = wn * 64 + n * 16 + r4;
            float4 bv = *reinterpret_cast<const float4*>(&bji[col0]);
            #pragma unroll
            for (int m = 0; m < 2; ++m) {
                int row = wm * 32 + m * 16 + l15;
                ushort4 ob;
                ob.x = f2bf(silu_f(acc[m][n][0] + bv.x));
                ob.y = f2bf(silu_f(acc[m][n][1] + bv.y));
                ob.z = f2bf(silu_f(acc[m][n][2] + bv.z));
                ob.w = f2bf(silu_f(acc[m][n][3] + bv.w));
                *reinterpret_cast<ushort4*>(&E1[(size_t)(bm + row) * H_DIM + col0]) = ob;
            }
        }
    }
    // KJ * gate -> IT (bf16 temp)
    {
        f32x4 acc[2][4] = {};
        mm128_pipe_T(XT, Wkjh, Wkjl, pre, nullptr, nullptr, wm, wn, l15, khalf, acc);
        float r8v[2][8];
        #pragma unroll
        for (int m = 0; m < 2; ++m) {
            int grow = bm + wm * 32 + m * 16 + l15;
            const float2* rp = reinterpret_cast<const float2*>(&rbf[(size_t)grow * NRAD]);
            float2 q0 = rp[0], q1 = rp[1], q2 = rp[2];
            float rv[NRAD] = {q0.x, q0.y, q1.x, q1.y, q2.x, q2.y};
            #pragma unroll
            for (int j = 0; j < 8; ++j) r8v[m][j] = 0.f;
            #pragma unroll
            for (int k = 0; k < NRAD; ++k)
                #pragma unroll
                for (int j = 0; j < 8; ++j)
                    r8v[m][j] = fmaf(rv[k], W1[k * BAS + j], r8v[m][j]);
        }
        #pragma unroll
        for (int n = 0; n < 4; ++n) {
            int col0 = wn * 64 + n * 16 + r4;
            float4 bvf = *reinterpret_cast<const float4*>(&bkj[col0]);
            float bv[4] = {bvf.x, bvf.y, bvf.z, bvf.w};
            float wrv[8][4];
            #pragma unroll
            for (int j = 0; j < 8; ++j) {
                float4 wf = *reinterpret_cast<const float4*>(&Wr2[j * H_DIM + col0]);
                wrv[j][0] = wf.x; wrv[j][1] = wf.y; wrv[j][2] = wf.z; wrv[j][3] = wf.w;
            }
            #pragma unroll
            for (int m = 0; m < 2; ++m) {
                int row = wm * 32 + m * 16 + l15;
                float v[4];
                #pragma unroll
                for (int r = 0; r < 4; ++r) {
                    float t = silu_f(acc[m][n][r] + bv[r]);
                    float g = 0.f;
                    #pragma unroll
                    for (int j = 0; j < 8; ++j)
                        g = fmaf(r8v[m][j], wrv[j][r], g);
                    v[r] = t * g;
                }
                st_bf4(IT, row, col0, 256, v);
            }
        }
    }
    __syncthreads();

    // DOWN (N=64), 2-term from IT -> C1 (bf16)
    {
        f32x4 acc[2][2] = {};
        #pragma unroll
        for (int k0 = 0; k0 < 128; k0 += 32) {
            bf16x8 bh[2], bl[2];
            #pragma unroll
            for (int n = 0; n < 2; ++n) {
                size_t bo = (size_t)(wn * 32 + n * 16 + l15) * 128 + k0 + khalf;
                bh[n] = *reinterpret_cast<const bf16x8*>(Wdnh + bo);
                bl[n] = *reinterpret_cast<const bf16x8*>(Wdnl + bo);
            }
            __builtin_amdgcn_s_setprio(1);
            #pragma unroll
            for (int m = 0; m < 2; ++m) {
                int row = wm * 32 + m * 16 + l15;
                int off = (row * 256 + (k0 + khalf) * 2) ^ ((row & 7) << 4);
                bf16x8 a = *reinterpret_cast<const bf16x8*>(IT + off);
                #pragma unroll
                for (int n = 0; n < 2; ++n) {
                    acc[m][n] = __builtin_amdgcn_mfma_f32_16x16x32_bf16(bh[n], a, acc[m][n], 0, 0, 0);
                    acc[m][n] = __builtin_amdgcn_mfma_f32_16x16x32_bf16(bl[n], a, acc[m][n], 0, 0, 0);
                }
            }
            __builtin_amdgcn_s_setprio(0);
        }
        #pragma unroll
        for (int n = 0; n < 2; ++n) {
            int col0 = wn * 32 + n * 16 + r4;
            #pragma unroll
            for (int m = 0; m < 2; ++m) {
                int row = wm * 32 + m * 16 + l15;
                ushort4 ob;
                ob.x = f2bf(silu_f(acc[m][n][0]));
                ob.y = f2bf(silu_f(acc[m][n][1]));
                ob.z = f2bf(silu_f(acc[m][n][2]));
                ob.w = f2bf(silu_f(acc[m][n][3]));
                *reinterpret_cast<ushort4*>(&C1[(size_t)(bm + row) * INT_DIM + col0]) = ob;
            }
        }
    }
}

// ---------------------------------------------------------------------------
// post/out bodies sharing 32KB smem
// ---------------------------------------------------------------------------
struct ChainP {
    const u16 *uph, *upl;
    const u16 *b0h, *b0l, *b1h, *b1l;
    const u16 *lnh, *lnl;
    const u16 *a0h, *a0l, *a1h, *a1l, *a2h, *a2l, *a3h, *a3l;
    const float *bb0, *bb1, *blin, *ba0, *ba1, *ba2, *ba3;
    // fused pre-part for NEXT interaction block (doPre != 0)
    int doPre;
    const float *rbfp, *preW1, *nbji, *nbkj, *nwr2;
    const u16 *njih, *njil, *nkjh, *nkjl, *ndnh, *ndnl;
    u16 *nE1, *nC1;
};
struct OutP {
    const float* TN;
    const u16 *Uh, *Ul; const float* bu;
    const u16 *L0h, *L0l; const float* b0;
    const u16 *L1h, *L1l; const float* b1;
    const u16 *L2h, *L2l; const float* b2;
    const float* Wo; float* P;
};

__device__ __forceinline__ void post_chain_body(
    char* smem, int bx,
    const u16* __restrict__ AGG, const u16* __restrict__ E1,
    const u16* __restrict__ X, const ChainP& p, u16* __restrict__ OUT)
{
    char* SB = smem;             // carrier S bf16 [64][128] stride 256 (16KB)
    char* TB = smem + 16384;     // TMP bf16 [64][128] stride 256 (16KB); AGG staging at start
    char* GB = TB;               // bf16-only AGG, stride 128 (8KB)

    const int tid  = threadIdx.x;
    const int lane = tid & 63;
    const int w    = tid >> 6;
    const int wm   = w >> 1, wn = w & 1;
    const int bm   = bx * 64;
    const int l15  = lane & 15;
    const int khalf = (lane >> 4) * 8;
    const int r4   = (lane >> 4) * 4;

    BF8x4 pre = loadB64f(p.uph, p.upl, 0, wn, l15, khalf);

    // stage AGG [64][64] bf16 (stride 128)
    {
        int r  = tid >> 2;
        int c0 = (tid & 3) * 16;
        const ushort4* pg = reinterpret_cast<const ushort4*>(&AGG[(size_t)(bm + r) * INT_DIM + c0]);
        const int swz = (r & 7) << 4;
        #pragma unroll
        for (int q = 0; q < 4; ++q) {
            ushort4 v = pg[q];
            int off = (r * 128 + c0 * 2 + q * 8) ^ swz;
            *reinterpret_cast<ushort4*>(GB + off) = v;
        }
    }
    __syncthreads();

    f32x4 acc[2][4];
    #define ZACC { _Pragma("unroll") for (int m = 0; m < 2; ++m) \
                   _Pragma("unroll") for (int n = 0; n < 4; ++n) \
                       acc[m][n] = f32x4{0.f, 0.f, 0.f, 0.f}; }

    // S1: UP (K=64, 2-term), h0 = E1 + silu -> S (bf16) ; prefetch Wb0
    ZACC
    mm64_pipe_T(GB, p.uph, p.upl, pre, p.b0h, p.b0l, wm, wn, l15, khalf, acc);
    #pragma unroll
    for (int n = 0; n < 4; ++n) {
        int col0 = wn * 64 + n * 16 + r4;
        #pragma unroll
        for (int m = 0; m < 2; ++m) {
            int row = wm * 32 + m * 16 + l15;
            ushort4 e = *reinterpret_cast<const ushort4*>(&E1[(size_t)(bm + row) * H_DIM + col0]);
            float v[4];
            v[0] = bf2f(e.x) + silu_f(acc[m][n][0]);
            v[1] = bf2f(e.y) + silu_f(acc[m][n][1]);
            v[2] = bf2f(e.z) + silu_f(acc[m][n][2]);
            v[3] = bf2f(e.w) + silu_f(acc[m][n][3]);
            st_bf4(SB, row, col0, 256, v);
        }
    }
    __syncthreads();

    // PLAIN: S -> TMP (bf16)
    #define STAGE_PLAIN(WH, WL, BIAS, NWH, NWL)                                         \
    {                                                                                   \
        ZACC                                                                            \
        mm128_pipe_T(SB, WH, WL, pre, NWH, NWL, wm, wn, l15, khalf, acc);               \
        _Pragma("unroll")                                                               \
        for (int n = 0; n < 4; ++n) {                                                   \
            int col0 = wn * 64 + n * 16 + r4;                                           \
            float4 bv = *reinterpret_cast<const float4*>(&BIAS[col0]);                  \
            _Pragma("unroll")                                                           \
            for (int m = 0; m < 2; ++m) {                                               \
                int row = wm * 32 + m * 16 + l15;                                       \
                float v[4];                                                             \
                v[0] = silu_f(acc[m][n][0] + bv.x);                                     \
                v[1] = silu_f(acc[m][n][1] + bv.y);                                     \
                v[2] = silu_f(acc[m][n][2] + bv.z);                                     \
                v[3] = silu_f(acc[m][n][3] + bv.w);                                     \
                st_bf4(TB, row, col0, 256, v);                                          \
            }                                                                           \
        }                                                                               \
        __syncthreads();                                                                \
    }

    // RES: TMP(bf16, 2-term) -> S += silu (bf16 carrier)
    #define STAGE_RES(WH, WL, BIAS, NWH, NWL)                                           \
    {                                                                                   \
        ZACC                                                                            \
        mm128_pipe_T(TB, WH, WL, pre, NWH, NWL, wm, wn, l15, khalf, acc);               \
        _Pragma("unroll")                                                               \
        for (int n = 0; n < 4; ++n) {                                                   \
            int col0 = wn * 64 + n * 16 + r4;                                           \
            float4 bv = *reinterpret_cast<const float4*>(&BIAS[col0]);                  \
            _Pragma("unroll")                                                           \
            for (int m = 0; m < 2; ++m) {                                               \
                int row = wm * 32 + m * 16 + l15;                                       \
                float v[4];                                                             \
                ld_bf4(SB, row, col0, 256, v);                                          \
                v[0] += silu_f(acc[m][n][0] + bv.x);                                    \
                v[1] += silu_f(acc[m][n][1] + bv.y);                                    \
                v[2] += silu_f(acc[m][n][2] + bv.z);                                    \
                v[3] += silu_f(acc[m][n][3] + bv.w);                                    \
                st_bf4(SB, row, col0, 256, v);                                          \
            }                                                                           \
        }                                                                               \
        __syncthreads();                                                                \
    }

    // S2: temp = silu(S@Wb0+bb0); S3: S += silu(temp@Wb1+bb1)
    STAGE_PLAIN(p.b0h, p.b0l, p.bb0, p.b1h, p.b1l)
    STAGE_RES(p.b1h, p.b1l, p.bb1, p.lnh, p.lnl)

    // S4: x1 = silu(S@Wlin+blin) + X -> S in-place (barrier between read & write)
    {
        ZACC
        mm128_pipe_T(SB, p.lnh, p.lnl, pre, p.a0h, p.a0l, wm, wn, l15, khalf, acc);
        __syncthreads();   // all waves done reading S before overwrite
        #pragma unroll
        for (int n = 0; n < 4; ++n) {
            int col0 = wn * 64 + n * 16 + r4;
            float4 bv = *reinterpret_cast<const float4*>(&p.blin[col0]);
            #pragma unroll
            for (int m = 0; m < 2; ++m) {
                int row = wm * 32 + m * 16 + l15;
                ushort4 xv = *reinterpret_cast<const ushort4*>(&X[(size_t)(bm + row) * H_DIM + col0]);
                float v[4];
                v[0] = silu_f(acc[m][n][0] + bv.x) + bf2f(xv.x);
                v[1] = silu_f(acc[m][n][1] + bv.y) + bf2f(xv.y);
                v[2] = silu_f(acc[m][n][2] + bv.z) + bf2f(xv.z);
                v[3] = silu_f(acc[m][n][3] + bv.w) + bf2f(xv.w);
                st_bf4(SB, row, col0, 256, v);
            }
        }
        __syncthreads();
    }

    STAGE_PLAIN(p.a0h, p.a0l, p.ba0, p.a1h, p.a1l)
    STAGE_RES(p.a1h, p.a1l, p.ba1, p.a2h, p.a2l)
    STAGE_PLAIN(p.a2h, p.a2l, p.ba2, p.a3h, p.a3l)

    // S8: OUT(bf16) = S + silu(temp@Wa3+ba3); XT(=SB) := bf16(OUT) if doPre
    {
        ZACC
        mm128_pipe_T(TB, p.a3h, p.a3l, pre,
                     p.doPre ? p.njih : nullptr, p.doPre ? p.njil : nullptr,
                     wm, wn, l15, khalf, acc);
        #pragma unroll
        for (int n = 0; n < 4; ++n) {
            int col0 = wn * 64 + n * 16 + r4;
            float4 bv = *reinterpret_cast<const float4*>(&p.ba3[col0]);
            #pragma unroll
            for (int m = 0; m < 2; ++m) {
                int row = wm * 32 + m * 16 + l15;
                float v[4];
                ld_bf4(SB, row, col0, 256, v);
                ushort4 ob;
                ob.x = f2bf(v[0] + silu_f(acc[m][n][0] + bv.x));
                ob.y = f2bf(v[1] + silu_f(acc[m][n][1] + bv.y));
                ob.z = f2bf(v[2] + silu_f(acc[m][n][2] + bv.z));
                ob.w = f2bf(v[3] + silu_f(acc[m][n][3] + bv.w));
                *reinterpret_cast<ushort4*>(&OUT[(size_t)(bm + row) * H_DIM + col0]) = ob;
                if (p.doPre) {
                    int offx = (row * 256 + col0 * 2) ^ ((row & 7) << 4);
                    *reinterpret_cast<ushort4*>(SB + offx) = ob;   // XT = bf16(OUT)
                }
            }
        }
    }

    // ---- fused pre-part for NEXT block: XT=SB holds bf16(x_{b+1}) rows bm..bm+64
    if (p.doPre) {
        char* XT = SB;
        char* IT = TB;
        __syncthreads();   // XT complete before cross-row MFMA reads

        // JI -> nE1 (prefetch KJ)
        {
            ZACC
            mm128_pipe_T(XT, p.njih, p.njil, pre, p.nkjh, p.nkjl, wm, wn, l15, khalf, acc);
            #pragma unroll
            for (int n = 0; n < 4; ++n) {
                int col0 = wn * 64 + n * 16 + r4;
                float4 bv = *reinterpret_cast<const float4*>(&p.nbji[col0]);
                #pragma unroll
                for (int m = 0; m < 2; ++m) {
                    int row = wm * 32 + m * 16 + l15;
                    ushort4 ob;
                    ob.x = f2bf(silu_f(acc[m][n][0] + bv.x));
                    ob.y = f2bf(silu_f(acc[m][n][1] + bv.y));
                    ob.z = f2bf(silu_f(acc[m][n][2] + bv.z));
                    ob.w = f2bf(silu_f(acc[m][n][3] + bv.w));
                    *reinterpret_cast<ushort4*>(&p.nE1[(size_t)(bm + row) * H_DIM + col0]) = ob;
                }
            }
        }
        // KJ * gate -> IT
        {
            ZACC
            mm128_pipe_T(XT, p.nkjh, p.nkjl, pre, nullptr, nullptr, wm, wn, l15, khalf, acc);
            float r8v[2][8];
            #pragma unroll
            for (int m = 0; m < 2; ++m) {
                int grow = bm + wm * 32 + m * 16 + l15;
                const float2* rp = reinterpret_cast<const float2*>(&p.rbfp[(size_t)grow * NRAD]);
                float2 q0 = rp[0], q1 = rp[1], q2 = rp[2];
                float rv[NRAD] = {q0.x, q0.y, q1.x, q1.y, q2.x, q2.y};
                #pragma unroll
                for (int j = 0; j < 8; ++j) r8v[m][j] = 0.f;
                #pragma unroll
                for (int k = 0; k < NRAD; ++k)
                    #pragma unroll
                    for (int j = 0; j < 8; ++j)
                        r8v[m][j] = fmaf(rv[k], p.preW1[k * BAS + j], r8v[m][j]);
            }
            #pragma unroll
            for (int n = 0; n < 4; ++n) {
                int col0 = wn * 64 + n * 16 + r4;
                float4 bvf = *reinterpret_cast<const float4*>(&p.nbkj[col0]);
                float bv[4] = {bvf.x, bvf.y, bvf.z, bvf.w};
                float wrv[8][4];
                #pragma unroll
                for (int j = 0; j < 8; ++j) {
                    float4 wf = *reinterpret_cast<const float4*>(&p.nwr2[j * H_DIM + col0]);
                    wrv[j][0] = wf.x; wrv[j][1] = wf.y; wrv[j][2] = wf.z; wrv[j][3] = wf.w;
                }
                #pragma unroll
                for (int m = 0; m < 2; ++m) {
                    int row = wm * 32 + m * 16 + l15;
                    float v[4];
                    #pragma unroll
                    for (int r = 0; r < 4; ++r) {
                        float t = silu_f(acc[m][n][r] + bv[r]);
                        float g = 0.f;
                        #pragma unroll
                        for (int j = 0; j < 8; ++j)
                            g = fmaf(r8v[m][j], wrv[j][r], g);
                        v[r] = t * g;
                    }
                    st_bf4(IT, row, col0, 256, v);
                }
            }
        }
        __syncthreads();

        // DOWN (N=64), 2-term from IT -> nC1 (bf16)
        {
            f32x4 acc2[2][2] = {};
            #pragma unroll
            for (int k0 = 0; k0 < 128; k0 += 32) {
                bf16x8 bh[2], bl[2];
                #pragma unroll
                for (int n = 0; n < 2; ++n) {
                    size_t bo = (size_t)(wn * 32 + n * 16 + l15) * 128 + k0 + khalf;
                    bh[n] = *reinterpret_cast<const bf16x8*>(p.ndnh + bo);
                    bl[n] = *reinterpret_cast<const bf16x8*>(p.ndnl + bo);
                }
                __builtin_amdgcn_s_setprio(1);
                #pragma unroll
                for (int m = 0; m < 2; ++m) {
                    int row = wm * 32 + m * 16 + l15;
                    int off = (row * 256 + (k0 + khalf) * 2) ^ ((row & 7) << 4);
                    bf16x8 a = *reinterpret_cast<const bf16x8*>(IT + off);
                    #pragma unroll
                    for (int n = 0; n < 2; ++n) {
                        acc2[m][n] = __builtin_amdgcn_mfma_f32_16x16x32_bf16(bh[n], a, acc2[m][n], 0, 0, 0);
                        acc2[m][n] = __builtin_amdgcn_mfma_f32_16x16x32_bf16(bl[n], a, acc2[m][n], 0, 0, 0);
                    }
                }
                __builtin_amdgcn_s_setprio(0);
            }
            #pragma unroll
            for (int n = 0; n < 2; ++n) {
                int col0 = wn * 32 + n * 16 + r4;
                #pragma unroll
                for (int m = 0; m < 2; ++m) {
                    int row = wm * 32 + m * 16 + l15;
                    ushort4 ob;
                    ob.x = f2bf(silu_f(acc2[m][n][0]));
                    ob.y = f2bf(silu_f(acc2[m][n][1]));
                    ob.z = f2bf(silu_f(acc2[m][n][2]));
                    ob.w = f2bf(silu_f(acc2[m][n][3]));
                    *reinterpret_cast<ushort4*>(&p.nC1[(size_t)(bm + row) * INT_DIM + col0]) = ob;
                }
            }
        }
    }
    #undef STAGE_PLAIN
    #undef STAGE_RES
    #undef ZACC
}

// out_chain: 32KB, bf16 S/TMP
__device__ __forceinline__ void out_chain_body(char* smem, int bx, const OutP& o)
{
    char* RA = smem;             // region A (16KB): X bf16 [32][128] stride 256; then TMP bf16 [32][256] stride 512
    char* RB = smem + 16384;     // region B (16KB): S bf16 [32][256] stride 512

    const int tid  = threadIdx.x;
    const int lane = tid & 63;
    const int wn   = tid >> 6;
    const int bm   = bx * 32;
    const int l15  = lane & 15;
    const int khalf = (lane >> 4) * 8;
    const int r4   = (lane >> 4) * 4;

    // stage TN tile [32][128] bf16 (stride 256) into RA
    {
        int r  = tid >> 3;
        int c0 = (tid & 7) * 16;
        const float* p = &o.TN[(size_t)(bm + r) * H_DIM + c0];
        const int swz = (r & 7) << 4;
        #pragma unroll
        for (int q = 0; q < 4; ++q) {
            float4 f = *reinterpret_cast<const float4*>(p + q * 4);
            ushort4 hh;
            hh.x = f2bf(f.x); hh.y = f2bf(f.y); hh.z = f2bf(f.z); hh.w = f2bf(f.w);
            int off = (r * 256 + c0 * 2 + q * 8) ^ swz;
            *reinterpret_cast<ushort4*>(RA + off) = hh;
        }
    }
    __syncthreads();

    f32x4 acc[2][4];
    #define ZACC { _Pragma("unroll") for (int m = 0; m < 2; ++m) \
                   _Pragma("unroll") for (int n = 0; n < 4; ++n) \
                       acc[m][n] = f32x4{0.f, 0.f, 0.f, 0.f}; }

    // up: A=X bf16 (stride 256, rows 0..31, wm=0), out pre-act+bias -> S (RB)
    {
        ZACC
        BF8x4 pre = loadB128f(o.Uh, o.Ul, 0, wn, l15, khalf);
        mm128_pipe_T(RA, o.Uh, o.Ul, pre, nullptr, nullptr, 0, wn, l15, khalf, acc);
        #pragma unroll
        for (int n = 0; n < 4; ++n) {
            int col0 = wn * 64 + n * 16 + r4;
            float4 bv = *reinterpret_cast<const float4*>(&o.bu[col0]);
            #pragma unroll
            for (int m = 0; m < 2; ++m) {
                int row = m * 16 + l15;
                float v[4] = {acc[m][n][0] + bv.x, acc[m][n][1] + bv.y,
                              acc[m][n][2] + bv.z, acc[m][n][3] + bv.w};
                st_bf4(RB, row, col0, 512, v);
            }
        }
        __syncthreads();
    }

    // L0: A=S (RB) -> TMP (RA, X dead after barrier above)
    {
        ZACC
        BF8x4 cur = loadB256f(o.L0h, o.L0l, 0, wn, l15, khalf);
        #pragma unroll
        for (int k = 0; k < 8; ++k) {
            BF8x4 nxt;
            if (k < 7) nxt = loadB256f(o.L0h, o.L0l, 32 * (k + 1), wn, l15, khalf);
            mfma_cluster512_T(RB, 32 * k, l15, khalf, cur, acc);
            if (k < 7) cur = nxt;
        }
        #pragma unroll
        for (int n = 0; n < 4; ++n) {
            int col0 = wn * 64 + n * 16 + r4;
            float4 bv = *reinterpret_cast<const float4*>(&o.b0[col0]);
            #pragma unroll
            for (int m = 0; m < 2; ++m) {
                int row = m * 16 + l15;
                float v[4];
                v[0] = silu_f(acc[m][n][0] + bv.x);
                v[1] = silu_f(acc[m][n][1] + bv.y);
                v[2] = silu_f(acc[m][n][2] + bv.z);
                v[3] = silu_f(acc[m][n][3] + bv.w);
                st_bf4(RA, row, col0, 512, v);
            }
        }
        __syncthreads();
    }

    // L1: A=TMP (RA) -> S (RB)
    {
        ZACC
        BF8x4 cur = loadB256f(o.L1h, o.L1l, 0, wn, l15, khalf);
        #pragma unroll
        for (int k = 0; k < 8; ++k) {
            BF8x4 nxt;
            if (k < 7) nxt = loadB256f(o.L1h, o.L1l, 32 * (k + 1), wn, l15, khalf);
            mfma_cluster512_T(RA, 32 * k, l15, khalf, cur, acc);
            if (k < 7) cur = nxt;
        }
        #pragma unroll
        for (int n = 0; n < 4; ++n) {
            int col0 = wn * 64 + n * 16 + r4;
            float4 bv = *reinterpret_cast<const float4*>(&o.b1[col0]);
            #pragma unroll
            for (int m = 0; m < 2; ++m) {
                int row = m * 16 + l15;
                float v[4];
                v[0] = silu_f(acc[m][n][0] + bv.x);
                v[1] = silu_f(acc[m][n][1] + bv.y);
                v[2] = silu_f(acc[m][n][2] + bv.z);
                v[3] = silu_f(acc[m][n][3] + bv.w);
                st_bf4(RB, row, col0, 512, v);
            }
        }
        __syncthreads();
    }

    // L2: A=S (RB) -> S in-place (barrier between read & write)
    {
        ZACC
        BF8x4 cur = loadB256f(o.L2h, o.L2l, 0, wn, l15, khalf);
        #pragma unroll
        for (int k = 0; k < 8; ++k) {
            BF8x4 nxt;
            if (k < 7) nxt = loadB256f(o.L2h, o.L2l, 32 * (k + 1), wn, l15, khalf);
            mfma_cluster512_T(RB, 32 * k, l15, khalf, cur, acc);
            if (k < 7) cur = nxt;
        }
        __syncthreads();
        #pragma unroll
        for (int n = 0; n < 4; ++n) {
            int col0 = wn * 64 + n * 16 + r4;
            float4 bv = *reinterpret_cast<const float4*>(&o.b2[col0]);
            #pragma unroll
            for (int m = 0; m < 2; ++m) {
                int row = m * 16 + l15;
                float v[4];
                v[0] = silu_f(acc[m][n][0] + bv.x);
                v[1] = silu_f(acc[m][n][1] + bv.y);
                v[2] = silu_f(acc[m][n][2] + bv.z);
                v[3] = silu_f(acc[m][n][3] + bv.w);
                st_bf4(RB, row, col0, 512, v);
            }
        }
        __syncthreads();
    }

    // final: P[bm+row] += dot(S[row][:256], Wo[:256]); 8 threads per row
    {
        int row  = tid >> 3;
        int part = tid & 7;
        float s = 0.f;
        int cbase = part * 32;
        #pragma unroll
        for (int c4 = 0; c4 < 32; c4 += 4) {
            float v[4];
            ld_bf4(RB, row, cbase + c4, 512, v);
            float4 wv = *reinterpret_cast<const float4*>(&o.Wo[cbase + c4]);
            s = fmaf(v[0], wv.x, s);
            s = fmaf(v[1], wv.y, s);
            s = fmaf(v[2], wv.z, s);
            s = fmaf(v[3], wv.w, s);
        }
        s += __shfl_xor(s, 1);
        s += __shfl_xor(s, 2);
        s += __shfl_xor(s, 4);
        if (part == 0) o.P[bm + row] += s;
    }
    #undef ZACC
}

__global__ __launch_bounds__(256, 2) void post_fused(
    int npost,
    const u16* __restrict__ AGG, const u16* __restrict__ E1,
    const u16* __restrict__ X, ChainP p, u16* __restrict__ OUT, OutP o)
{
    __shared__ char smem[32768];
    if ((int)blockIdx.x < npost)
        post_chain_body(smem, blockIdx.x, AGG, E1, X, p, OUT);
    else
        out_chain_body(smem, blockIdx.x - npost, o);
}

// ---------------------------------------------------------------------------
// Fused gather: blocks < GT do triplet aggregation, rest do out_gather.
// ---------------------------------------------------------------------------
__device__ __forceinline__ float dot8_bf(uint4 r, const float* w2) {
    float s;
    s  = bf2f((u16)(r.x)) * w2[0] + bf2f((u16)(r.x >> 16)) * w2[1];
    s += bf2f((u16)(r.y)) * w2[2] + bf2f((u16)(r.y >> 16)) * w2[3];
    s += bf2f((u16)(r.z)) * w2[4] + bf2f((u16)(r.z >> 16)) * w2[5];
    s += bf2f((u16)(r.w)) * w2[6] + bf2f((u16)(r.w >> 16)) * w2[7];
    return s;
}

__device__ __forceinline__ void triplet_body(
    int bx, int nblk,
    const u16* __restrict__ ps8b, const float* __restrict__ Wsb2,
    const u16* __restrict__ xkj, const int* __restrict__ pkj,
    const int* __restrict__ tptr, const int* __restrict__ tcnt,
    u16* __restrict__ agg)
{
    const int lane = threadIdx.x & 63;
    int wid = bx * 4 + (threadIdx.x >> 6);
    const int nw = nblk * 4;
    float w2[BAS];
    #pragma unroll
    for (int j = 0; j < BAS; ++j) w2[j] = Wsb2[j * INT_DIM + lane];

    for (int e = wid; e < E_EDGES; e += nw) {
        int start = tptr[e];
        int end   = start + tcnt[e];
        float acc0 = 0.f, acc1 = 0.f;
        int i = start;
        for (; i + 1 < end; i += 2) {
            uint4 ra = *reinterpret_cast<const uint4*>(&ps8b[(size_t)i * BAS]);
            uint4 rb = *reinterpret_cast<const uint4*>(&ps8b[(size_t)(i + 1) * BAS]);
            int e0 = pkj[i], e1 = pkj[i + 1];
            float s0 = dot8_bf(ra, w2);
            float s1 = dot8_bf(rb, w2);
            acc0 = fmaf(bf2f(xkj[(size_t)e0 * INT_DIM + lane]), s0, acc0);
            acc1 = fmaf(bf2f(xkj[(size_t)e1 * INT_DIM + lane]), s1, acc1);
        }
        if (i < end) {
            uint4 ra = *reinterpret_cast<const uint4*>(&ps8b[(size_t)i * BAS]);
            int e0 = pkj[i];
            acc0 = fmaf(bf2f(xkj[(size_t)e0 * INT_DIM + lane]), dot8_bf(ra, w2), acc0);
        }
        agg[(size_t)e * INT_DIM + lane] = f2bf(acc0 + acc1);
    }
}

__device__ __forceinline__ void out_gather_body(
    int bx, int nblk,
    const float* __restrict__ rbf, const float* __restrict__ Wor,
    const u16* __restrict__ x,
    const int* __restrict__ eptr, const int* __restrict__ ecnt,
    const int* __restrict__ eperm, float* __restrict__ tN)
{
    const int lane = threadIdx.x & 63;
    int wid = bx * 4 + (threadIdx.x >> 6);
    const int nw = nblk * 4;
    float wr0[NRAD], wr1[NRAD];
    #pragma unroll
    for (int k = 0; k < NRAD; ++k) {
        wr0[k] = Wor[k * H_DIM + lane];
        wr1[k] = Wor[k * H_DIM + lane + 64];
    }
    for (int n = wid; n < N_NODES; n += nw) {
        int start = eptr[n];
        int end   = start + ecnt[n];
        float a0 = 0.f, a1 = 0.f;
        for (int i = start; i < end; ++i) {
            int e = eperm[i];
            const float2* rp = reinterpret_cast<const float2*>(&rbf[(size_t)e * NRAD]);
            float2 r0 = rp[0], r1 = rp[1], r2 = rp[2];
            float rA = r0.x*wr0[0] + r0.y*wr0[1] + r1.x*wr0[2]
                     + r1.y*wr0[3] + r2.x*wr0[4] + r2.y*wr0[5];
            float rB = r0.x*wr1[0] + r0.y*wr1[1] + r1.x*wr1[2]
                     + r1.y*wr1[3] + r2.x*wr1[4] + r2.y*wr1[5];
            a0 = fmaf(rA, bf2f(x[(size_t)e * H_DIM + lane]), a0);
            a1 = fmaf(rB, bf2f(x[(size_t)e * H_DIM + lane + 64]), a1);
        }
        tN[(size_t)n * H_DIM + lane] = a0;
        tN[(size_t)n * H_DIM + lane + 64] = a1;
    }
}

__global__ __launch_bounds__(256) void gather_fused(
    int GT,
    const u16* __restrict__ ps8b, const float* __restrict__ Wsb2,
    const u16* __restrict__ xkj, const int* __restrict__ pkj,
    const int* __restrict__ tptr, const int* __restrict__ tcnt,
    u16* __restrict__ agg,
    const float* __restrict__ rbf, const float* __restrict__ Wor,
    const u16* __restrict__ x,
    const int* __restrict__ eptr, const int* __restrict__ ecnt,
    const int* __restrict__ eperm, float* __restrict__ tN)
{
    int bx = blockIdx.x;
    if (bx < GT)
        triplet_body(bx, GT, ps8b, Wsb2, xkj, pkj, tptr, tcnt, agg);
    else
        out_gather_body(bx - GT, gridDim.x - GT, rbf, Wor, x, eptr, ecnt, eperm, tN);
}

// ---------------------------------------------------------------------------
// CSR build kernels
// ---------------------------------------------------------------------------
__global__ __launch_bounds__(256) void csr_count(
    const int* __restrict__ idx, int* __restrict__ cnt, int n)
{
    int i = blockIdx.x * 256 + threadIdx.x;
    if (i < n) atomicAdd(&cnt[idx[i]], 1);
}

__global__ __launch_bounds__(256) void scan_block(
    const int* __restrict__ cnt, int* __restrict__ ptr, int* __restrict__ bsum, int n)
{
    __shared__ int s[256];
    int i = blockIdx.x * 256 + threadIdx.x;
    int v = (i < n) ? cnt[i] : 0;
    s[threadIdx.x] = v;
    __syncthreads();
    #pragma unroll
    for (int off = 1; off < 256; off <<= 1) {
        int t = (threadIdx.x >= off) ? s[threadIdx.x - off] : 0;
        __syncthreads();
        s[threadIdx.x] += t;
        __syncthreads();
    }
    if (i < n) ptr[i] = s[threadIdx.x] - v;   // exclusive
    if (threadIdx.x == 255) bsum[blockIdx.x] = s[255];
}

__global__ __launch_bounds__(1024) void scan_aux(int* __restrict__ bsum, int nb)
{
    __shared__ int s[1024];
    int v = (threadIdx.x < nb) ? bsum[threadIdx.x] : 0;
    s[threadIdx.x] = v;
    __syncthreads();
    #pragma unroll
    for (int off = 1; off < 1024; off <<= 1) {
        int t = (threadIdx.x >= off) ? s[threadIdx.x - off] : 0;
        __syncthreads();
        s[threadIdx.x] += t;
        __syncthreads();
    }
    if (threadIdx.x < nb) bsum[threadIdx.x] = s[threadIdx.x] - v;
}

__global__ __launch_bounds__(256) void scan_add(
    int* __restrict__ ptr, const int* __restrict__ bsum, int n)
{
    int i = blockIdx.x * 256 + threadIdx.x;
    if (i < n) ptr[i] += bsum[blockIdx.x];
}

__global__ __launch_bounds__(256) void csr_fill(
    const int* __restrict__ idx, int* __restrict__ cursor,
    int* __restrict__ perm, int n)
{
    int i = blockIdx.x * 256 + threadIdx.x;
    if (i >= n) return;
    int pos = atomicAdd(&cursor[idx[i]], 1);
    perm[pos] = i;
}

// ---------------------------------------------------------------------------
// One-time: permuted sbf basis for ALL blocks + permuted idx_kj.
// ---------------------------------------------------------------------------
__global__ __launch_bounds__(256) void permute_s8(
    const float* __restrict__ sbf, const float* __restrict__ W1all,
    const int* __restrict__ idx_kj, const int* __restrict__ tperm,
    u16* __restrict__ ps8, int* __restrict__ pkj, int Tcount)
{
    __shared__ float Ws[NB * SBF_D * BAS];
    for (int i = threadIdx.x; i < NB * SBF_D * BAS; i += 256) Ws[i] = W1all[i];
    __syncthreads();
    int i = blockIdx.x * 256 + threadIdx.x;
    if (i >= Tcount) return;
    int t = tperm[i];
    pkj[i] = idx_kj[t];
    float s[SBF_D];
    {
        const float2* p2 = reinterpret_cast<const float2*>(&sbf[(size_t)t * SBF_D]);
        #pragma unroll
        for (int k = 0; k < SBF_D / 2; ++k) {
            float2 v = p2[k];
            s[2 * k] = v.x; s[2 * k + 1] = v.y;
        }
    }
    #pragma unroll
    for (int b = 0; b < NB; ++b) {
        const float* Wb_ = &Ws[b * SBF_D * BAS];
        float acc[BAS] = {};
        for (int k = 0; k < SBF_D; ++k) {
            float sv = s[k];
            #pragma unroll
            for (int j = 0; j < BAS; ++j)
                acc[j] = fmaf(sv, Wb_[k * BAS + j], acc[j]);
        }
        ushort4 o0 = make_ushort4(f2bf(acc[0]), f2bf(acc[1]), f2bf(acc[2]), f2bf(acc[3]));
        ushort4 o1 = make_ushort4(f2bf(acc[4]), f2bf(acc[5]), f2bf(acc[6]), f2bf(acc[7]));
        u16* op = &ps8[((size_t)b * Tcount + i) * BAS];
        *reinterpret_cast<ushort4*>(op) = o0;
        *reinterpret_cast<ushort4*>(op + 4) = o1;
    }
}

// ---------------------------------------------------------------------------
extern "C" void kernel_launch(void* const* d_in, const int* in_sizes, int n_in,
                              void* d_out, int out_size, void* d_ws, size_t ws_size,
                              hipStream_t stream)
{
    const float* x_in    = (const float*)d_in[0];
    const float* rbf     = (const float*)d_in[1];
    const float* sbf     = (const float*)d_in[2];
    const float* W_rbf1  = (const float*)d_in[3];
    const float* W_rbf2  = (const float*)d_in[4];
    const float* W_sbf1  = (const float*)d_in[5];
    const float* W_sbf2  = (const float*)d_in[6];
    const float* W_kj    = (const float*)d_in[7];
    const float* b_kj    = (const float*)d_in[8];
    const float* W_ji    = (const float*)d_in[9];
    const float* b_ji    = (const float*)d_in[10];
    const float* W_down  = (const float*)d_in[11];
    const float* W_up    = (const float*)d_in[12];
    const float* Wb      = (const float*)d_in[13];
    const float* bb      = (const float*)d_in[14];
    const float* Wa      = (const float*)d_in[15];
    const float* ba      = (const float*)d_in[16];
    const float* W_lin   = (const float*)d_in[17];
    const float* b_lin   = (const float*)d_in[18];
    const float* Wo_rbf  = (const float*)d_in[19];
    const float* Wo_up   = (const float*)d_in[20];
    const float* bo_up   = (const float*)d_in[21];
    const float* Wo_lins = (const float*)d_in[22];
    const float* bo_lins = (const float*)d_in[23];
    const float* Wo_out  = (const float*)d_in[24];
    const int*   idx_kj  = (const int*)d_in[25];
    const int*   idx_ji  = (const int*)d_in[26];
    const int*   idx_i   = (const int*)d_in[27];

    // workspace carve-up
    char* ws = (char*)d_ws;
    size_t off = 0;
    auto alloc = [&](size_t bytes) -> void* {
        void* p = (void*)(ws + off);
        off += (bytes + 255) & ~(size_t)255;
        return p;
    };
    u16*   X0B = (u16*)alloc((size_t)E_EDGES * H_DIM * 2);   // bf16 input x
    u16*   XAB = (u16*)alloc((size_t)E_EDGES * H_DIM * 2);
    u16*   XBB = (u16*)alloc((size_t)E_EDGES * H_DIM * 2);
    u16*   E1B = (u16*)alloc((size_t)E_EDGES * H_DIM * 2);   // bf16 E1
    u16*   C1B = (u16*)alloc((size_t)E_EDGES * INT_DIM * 2); // bf16 C1
    u16*   C2B = (u16*)alloc((size_t)E_EDGES * INT_DIM * 2); // bf16 C2
    float* TN  = (float*)alloc((size_t)N_NODES * H_DIM * 4);
    // split-bf16 transposed weights
    u16* HKJ = (u16*)alloc(4  * 16384 * 2); u16* LKJ = (u16*)alloc(4  * 16384 * 2);
    u16* HJI = (u16*)alloc(4  * 16384 * 2); u16* LJI = (u16*)alloc(4  * 16384 * 2);
    u16* HDN = (u16*)alloc(4  * 8192  * 2); u16* LDN = (u16*)alloc(4  * 8192  * 2);
    u16* HUP = (u16*)alloc(4  * 8192  * 2); u16* LUP = (u16*)alloc(4  * 8192  * 2);
    u16* HWB = (u16*)alloc(8  * 16384 * 2); u16* LWB = (u16*)alloc(8  * 16384 * 2);
    u16* HWA = (u16*)alloc(16 * 16384 * 2); u16* LWA = (u16*)alloc(16 * 16384 * 2);
    u16* HLN = (u16*)alloc(4  * 16384 * 2); u16* LLN = (u16*)alloc(4  * 16384 * 2);
    u16* HOU = (u16*)alloc(5  * 32768 * 2); u16* LOU = (u16*)alloc(5  * 32768 * 2);
    u16* HOL = (u16*)alloc(15 * 65536 * 2); u16* LOL = (u16*)alloc(15 * 65536 * 2);
    // CSR structures
    int* tcnt  = (int*)alloc((size_t)E_EDGES * 4);
    int* tptr  = (int*)alloc((size_t)E_EDGES * 4);
    int* tcur  = (int*)alloc((size_t)E_EDGES * 4);
    int* tperm = (int*)alloc((size_t)T_TRIP * 4);
    int* tbsum = (int*)alloc(1024 * 4);
    int* ecnt  = (int*)alloc((size_t)N_NODES * 4);
    int* eptr  = (int*)alloc((size_t)N_NODES * 4);
    int* ecur  = (int*)alloc((size_t)N_NODES * 4);
    int* eperm = (int*)alloc((size_t)E_EDGES * 4);
    int* ebsum = (int*)alloc(1024 * 4);
    // permuted triplet stream
    u16* PS8 = (u16*)alloc((size_t)NB * T_TRIP * BAS * 2);
    int* PKJ = (int*)alloc((size_t)T_TRIP * 4);
    (void)ws_size;

    auto prep = [&](const float* src, u16* hi, u16* lo, int K, int N, int cnt) {
        dim3 g((K * N + 255) / 256, cnt);
        hipLaunchKernelGGL(wprep, g, dim3(256), 0, stream, src, hi, lo, K, N);
    };
    prep(W_kj,    HKJ, LKJ, 128, 128, 4);
    prep(W_ji,    HJI, LJI, 128, 128, 4);
    prep(W_down,  HDN, LDN, 128, 64,  4);
    prep(W_up,    HUP, LUP, 64,  128, 4);
    prep(Wb,      HWB, LWB, 128, 128, 8);
    prep(Wa,      HWA, LWA, 128, 128, 16);
    prep(W_lin,   HLN, LLN, 128, 128, 4);
    prep(Wo_up,   HOU, LOU, 128, 256, 5);
    prep(Wo_lins, HOL, LOL, 256, 256, 15);

    // ---- convert input x to bf16
    hipLaunchKernelGGL(cvt_bf, dim3((E_EDGES * H_DIM / 4 + 255) / 256), dim3(256), 0, stream,
                       x_in, X0B, E_EDGES * H_DIM / 4);

    // ---- build triplet CSR (idx_ji: T entries -> E buckets)
    {
        const int nbT = (E_EDGES + 255) / 256;
        hipMemsetAsync(tcnt, 0, (size_t)E_EDGES * 4, stream);
        hipLaunchKernelGGL(csr_count, dim3((T_TRIP + 255) / 256), dim3(256), 0, stream,
                           idx_ji, tcnt, T_TRIP);
        hipLaunchKernelGGL(scan_block, dim3(nbT), dim3(256), 0, stream, tcnt, tptr, tbsum, E_EDGES);
        hipLaunchKernelGGL(scan_aux, dim3(1), dim3(1024), 0, stream, tbsum, nbT);
        hipLaunchKernelGGL(scan_add, dim3(nbT), dim3(256), 0, stream, tptr, tbsum, E_EDGES);
        hipMemcpyAsync(tcur, tptr, (size_t)E_EDGES * 4, hipMemcpyDeviceToDevice, stream);
        hipLaunchKernelGGL(csr_fill, dim3((T_TRIP + 255) / 256), dim3(256), 0, stream,
                           idx_ji, tcur, tperm, T_TRIP);
    }
    // ---- build node CSR (idx_i: E entries -> N buckets)
    {
        const int nbN = (N_NODES + 255) / 256;
        hipMemsetAsync(ecnt, 0, (size_t)N_NODES * 4, stream);
        hipLaunchKernelGGL(csr_count, dim3((E_EDGES + 255) / 256), dim3(256), 0, stream,
                           idx_i, ecnt, E_EDGES);
        hipLaunchKernelGGL(scan_block, dim3(nbN), dim3(256), 0, stream, ecnt, eptr, ebsum, N_NODES);
        hipLaunchKernelGGL(scan_aux, dim3(1), dim3(1024), 0, stream, ebsum, nbN);
        hipLaunchKernelGGL(scan_add, dim3(nbN), dim3(256), 0, stream, eptr, ebsum, N_NODES);
        hipMemcpyAsync(ecur, eptr, (size_t)N_NODES * 4, hipMemcpyDeviceToDevice, stream);
        hipLaunchKernelGGL(csr_fill, dim3((E_EDGES + 255) / 256), dim3(256), 0, stream,
                           idx_i, ecur, eperm, E_EDGES);
    }
    // ---- one-time permuted sbf basis for all blocks
    hipLaunchKernelGGL(permute_s8, dim3((T_TRIP + 255) / 256), dim3(256), 0, stream,
                       sbf, W_sbf1, idx_kj, tperm, PS8, PKJ, T_TRIP);

    float* P = (float*)d_out;
    hipMemsetAsync(P, 0, (size_t)N_NODES * sizeof(float), stream);

    auto make_outp = [&](int ob) {
        OutP o;
        o.TN = TN;
        o.Uh = HOU + (size_t)ob * 32768; o.Ul = LOU + (size_t)ob * 32768;
        o.bu = bo_up + (size_t)ob * OUT_EMB;
        o.L0h = HOL + (size_t)(ob * 3 + 0) * 65536; o.L0l = LOL + (size_t)(ob * 3 + 0) * 65536;
        o.b0 = bo_lins + (size_t)(ob * 3 + 0) * OUT_EMB;
        o.L1h = HOL + (size_t)(ob * 3 + 1) * 65536; o.L1l = LOL + (size_t)(ob * 3 + 1) * 65536;
        o.b1 = bo_lins + (size_t)(ob * 3 + 1) * OUT_EMB;
        o.L2h = HOL + (size_t)(ob * 3 + 2) * 65536; o.L2l = LOL + (size_t)(ob * 3 + 2) * 65536;
        o.b2 = bo_lins + (size_t)(ob * 3 + 2) * OUT_EMB;
        o.Wo = Wo_out + (size_t)ob * OUT_EMB;
        o.P = P;
        return o;
    };

    const u16* xcur = X0B;
    const int EB = E_EDGES / 64;  // 3125
    const int GT = 2048;

    // standalone pre_fuse only for b=0
    hipLaunchKernelGGL(pre_fuse, dim3(EB), dim3(256), 0, stream,
                       xcur, rbf, W_rbf1,
                       HJI, LJI, b_ji,
                       HKJ, LKJ, b_kj,
                       W_rbf2,
                       HDN, LDN,
                       E1B, C1B);

    for (int b = 0; b < NB; ++b) {
        u16* xnext = (b % 2 == 0) ? XAB : XBB;
        // 1) triplet aggregation || out_gather(ob=b, xcur)
        hipLaunchKernelGGL(gather_fused, dim3(GT + 2048), dim3(256), 0, stream,
                           GT,
                           PS8 + (size_t)b * T_TRIP * BAS, W_sbf2 + (size_t)b * BAS * INT_DIM,
                           C1B, PKJ, tptr, tcnt, C2B,
                           rbf, Wo_rbf + (size_t)b * NRAD * H_DIM, xcur,
                           eptr, ecnt, eperm, TN);
        // 2) post_chain(b) [+ fused pre(b+1)] || out_chain(ob=b)
        ChainP cp;
        cp.uph = HUP + (size_t)b * 8192;  cp.upl = LUP + (size_t)b * 8192;
        cp.b0h = HWB + (size_t)(b * 2 + 0) * 16384; cp.b0l = LWB + (size_t)(b * 2 + 0) * 16384;
        cp.b1h = HWB + (size_t)(b * 2 + 1) * 16384; cp.b1l = LWB + (size_t)(b * 2 + 1) * 16384;
        cp.lnh = HLN + (size_t)b * 16384; cp.lnl = LLN + (size_t)b * 16384;
        cp.a0h = HWA + (size_t)(b * 4 + 0) * 16384; cp.a0l = LWA + (size_t)(b * 4 + 0) * 16384;
        cp.a1h = HWA + (size_t)(b * 4 + 1) * 16384; cp.a1l = LWA + (size_t)(b * 4 + 1) * 16384;
        cp.a2h = HWA + (size_t)(b * 4 + 2) * 16384; cp.a2l = LWA + (size_t)(b * 4 + 2) * 16384;
        cp.a3h = HWA + (size_t)(b * 4 + 3) * 16384; cp.a3l = LWA + (size_t)(b * 4 + 3) * 16384;
        cp.bb0 = bb + (size_t)(b * 2 + 0) * H_DIM;
        cp.bb1 = bb + (size_t)(b * 2 + 1) * H_DIM;
        cp.blin = b_lin + (size_t)b * H_DIM;
        cp.ba0 = ba + (size_t)(b * 4 + 0) * H_DIM;
        cp.ba1 = ba + (size_t)(b * 4 + 1) * H_DIM;
        cp.ba2 = ba + (size_t)(b * 4 + 2) * H_DIM;
        cp.ba3 = ba + (size_t)(b * 4 + 3) * H_DIM;
        if (b < NB - 1) {
            int nb_ = b + 1;
            cp.doPre = 1;
            cp.rbfp  = rbf;
            cp.preW1 = W_rbf1 + (size_t)nb_ * NRAD * BAS;
            cp.njih = HJI + (size_t)nb_ * 16384; cp.njil = LJI + (size_t)nb_ * 16384;
            cp.nbji = b_ji + (size_t)nb_ * H_DIM;
            cp.nkjh = HKJ + (size_t)nb_ * 16384; cp.nkjl = LKJ + (size_t)nb_ * 16384;
            cp.nbkj = b_kj + (size_t)nb_ * H_DIM;
            cp.nwr2 = W_rbf2 + (size_t)nb_ * BAS * H_DIM;
            cp.ndnh = HDN + (size_t)nb_ * 8192; cp.ndnl = LDN + (size_t)nb_ * 8192;
            cp.nE1  = E1B; cp.nC1 = C1B;
        } else {
            cp.doPre = 0;
            cp.rbfp = nullptr; cp.preW1 = nullptr;
            cp.njih = nullptr; cp.njil = nullptr; cp.nbji = nullptr;
            cp.nkjh = nullptr; cp.nkjl = nullptr; cp.nbkj = nullptr;
            cp.nwr2 = nullptr; cp.ndnh = nullptr; cp.ndnl = nullptr;
            cp.nE1 = nullptr; cp.nC1 = nullptr;
        }
        OutP op = make_outp(b);
        hipLaunchKernelGGL(post_fused, dim3(EB + N_NODES / 32), dim3(256), 0, stream,
                           EB, C2B, E1B, xcur, cp, xnext, op);
        xcur = xnext;
    }
    // final output block ob=NB: out_gather(x_NB) then out_chain
    {
        OutP op = make_outp(NB);
        ChainP cp = {};  // unused
        hipLaunchKernelGGL(gather_fused, dim3(2048), dim3(256), 0, stream,
                           0,
                           PS8, W_sbf2, C1B, PKJ, tptr, tcnt, C2B,
                           rbf, Wo_rbf + (size_t)NB * NRAD * H_DIM, xcur,
                           eptr, ecnt, eperm, TN);
        hipLaunchKernelGGL(post_fused, dim3(N_NODES / 32), dim3(256), 0, stream,
                           0, C2B, E1B, xcur, cp, XAB, op);
    }
}